// Round 6
// baseline (20720.804 us; speedup 1.0000x reference)
//
#include <hip/hip_runtime.h>
#include <hip/hip_bf16.h>
#include <math.h>

#define T_LEN 128
#define BATCH 64
#define IND   512
#define HDIM  256
#define NS    8
#define H4    1024
#define NTHR  512
#define RPC   8          // rows per cluster
#define CSTRIDE 67584    // floats per cluster region in ws
#define WQK_BASE (1024 + 8 * CSTRIDE)   // per-cg Wq/Wk slice table

typedef unsigned long long ull;
typedef unsigned int uint;
typedef unsigned short ushort;

// ---- LLC-coherent accessors (bypass per-XCD L2): agent-scope relaxed atomics ----
__device__ __forceinline__ float gload(const float* p) {
  return __hip_atomic_load(p, __ATOMIC_RELAXED, __HIP_MEMORY_SCOPE_AGENT);
}
__device__ __forceinline__ float2 gload2(const float* p) {
  ull v = __hip_atomic_load((const ull*)p, __ATOMIC_RELAXED, __HIP_MEMORY_SCOPE_AGENT);
  return __builtin_bit_cast(float2, v);
}
__device__ __forceinline__ void gstore(float* p, float v) {
  __hip_atomic_store(p, v, __ATOMIC_RELAXED, __HIP_MEMORY_SCOPE_AGENT);
}
__device__ __forceinline__ void gstore2(float* p, float a, float b) {
  float2 t = make_float2(a, b);
  __hip_atomic_store((ull*)p, __builtin_bit_cast(ull, t), __ATOMIC_RELAXED, __HIP_MEMORY_SCOPE_AGENT);
}

__device__ __forceinline__ float2 bf2(uint u) {
  return make_float2(__uint_as_float(u << 16), __uint_as_float(u & 0xffff0000u));
}
// 8 bf16 weights vs 8 fp32 A values -> acc
__device__ __forceinline__ void fma8(float& acc, float4 x0, float4 x1, uint4 u) {
  float2 wA = bf2(u.x), wB = bf2(u.y), wC = bf2(u.z), wD = bf2(u.w);
  acc += x0.x * wA.x + x0.y * wA.y + x0.z * wB.x + x0.w * wB.y
       + x1.x * wC.x + x1.y * wC.y + x1.z * wD.x + x1.w * wD.y;
}

// fast tanh via hw exp
__device__ __forceinline__ float ftanh(float x) {
  float xc = fminf(fmaxf(x, -9.f), 9.f);
  float t = __expf(2.f * xc);
  return (t - 1.f) * __builtin_amdgcn_rcpf(t + 1.f);
}

extern "C" __global__ void init_ctrl(int* ctrl) {
  int t = blockIdx.x * blockDim.x + threadIdx.x;
  if (t < 1024) ctrl[t] = 0;
}

// ---------------- Xp = tanh(LN(X @ W_proj + b)) ----------------
extern "C" __global__ __launch_bounds__(256) void xp_kernel(
    const float* __restrict__ X, const float* __restrict__ Wp, const float* __restrict__ bp,
    const float* __restrict__ lns, const float* __restrict__ lnb, float* __restrict__ out_xp)
{
  __shared__ float Xs[8 * IND];
  __shared__ float Ys[8 * HDIM];
  const int tid = threadIdx.x;
  const size_t base = (size_t)blockIdx.x * 8;
  const float* Xb = X + base * IND;
  for (int e = tid; e < 8 * IND / 4; e += 256) ((float4*)Xs)[e] = ((const float4*)Xb)[e];
  __syncthreads();
  float acc[8];
#pragma unroll
  for (int r = 0; r < 8; ++r) acc[r] = 0.f;
  for (int k = 0; k < IND; ++k) {
    float wv = Wp[k * HDIM + tid];
#pragma unroll
    for (int r = 0; r < 8; ++r) acc[r] += Xs[r * IND + k] * wv;
  }
  float bpv = bp[tid];
#pragma unroll
  for (int r = 0; r < 8; ++r) Ys[r * HDIM + tid] = acc[r] + bpv;
  __syncthreads();
  int w = tid >> 6, lane = tid & 63;
  for (int rr = 0; rr < 2; ++rr) {
    int r = w * 2 + rr;
    float v[4]; float s1 = 0.f, s2 = 0.f;
#pragma unroll
    for (int e = 0; e < 4; ++e) { v[e] = Ys[r * HDIM + lane + 64 * e]; s1 += v[e]; s2 += v[e] * v[e]; }
#pragma unroll
    for (int off = 32; off > 0; off >>= 1) { s1 += __shfl_xor(s1, off, 64); s2 += __shfl_xor(s2, off, 64); }
    float m = s1 / 256.f;
    float iv = rsqrtf(s2 / 256.f - m * m + 1e-5f);
#pragma unroll
    for (int e = 0; e < 4; ++e) {
      int hd = lane + 64 * e;
      out_xp[(base + r) * HDIM + hd] = tanhf((v[e] - m) * iv * lns[hd] + lnb[hd]);
    }
  }
}

// ws float layout: [0..1023] int flags (cluster cl: ints [cl*64, cl*64+64)), 8 clusters;
// data base = 1024; per cluster cl (8 clusters of 8 rows), stride 67584:
//   QPRE +0 (2048), KPRE +2048 (16384), MB0 +18432 (16384), MB1 +34816 (16384),
//   Z1c +51200 (8192), Z2c +59392 (8192)
// WQK_BASE: 64 slices x 2080 floats (Wq own-cols at +0 [4x260], Wk at +1040)

// ---------------- main recurrent kernel: 8 clusters x 64 blocks, 2 blocks/CU ----------------
extern "C" __global__ __launch_bounds__(NTHR, 4) void omr_main(
    const float* __restrict__ Xp,
    const float* __restrict__ Wq, const float* __restrict__ bq,
    const float* __restrict__ lnqs, const float* __restrict__ lnqb,
    const float* __restrict__ Wk, const float* __restrict__ bk,
    const float* __restrict__ lnks, const float* __restrict__ lnkb,
    const float* __restrict__ Wbeta, const float* __restrict__ bbeta,
    const float* __restrict__ W1, const float* __restrict__ b1,
    const float* __restrict__ W2, const float* __restrict__ b2,
    const float* __restrict__ lns, const float* __restrict__ lnb,
    float* __restrict__ mem_out, float* __restrict__ probs_out, float* __restrict__ ws)
{
  const int tid = threadIdx.x;
  const int clid = blockIdx.x >> 6;  // cluster 0..7 (8 rows each)
  const int cg = blockIdx.x & 63;    // column group within cluster
  const int ZC0 = cg * 16;           // z1/z2 cols owned
  const int QC0 = cg * 4;            // q/k/h cols owned
  const int row0 = clid * RPC;
  const int w = tid >> 6, lane = tid & 63;
  const int rl = lane >> 3, cl = lane & 7;   // 8x8 lane grid: row rl, cols (cl, cl+8)

  // LDS ~79.8 KB -> 2 blocks/CU
  __shared__ ushort W1b[16 * 520];    // bf16 W1 col slice
  __shared__ ushort W2b[16 * 1032];   // bf16 W2 col slice
  __shared__ float hloc[RPC * 260];
  __shared__ float Ast[RPC * 260];
  __shared__ float Az[RPC * 260];     // staging (single buffer)
  __shared__ float redS[8 * 132];     // split-K partials (8x16 tile)
  __shared__ float cpS[64], rcpS[64], betaS[64];
  __shared__ float b1s[16], b2s[16], bqS[4], bkS[4], bbetaS[1];

  float* base_ = ws + 1024 + (size_t)clid * CSTRIDE;
  float* QPRE  = base_;
  float* KPRE  = base_ + 2048;
  float* MB0   = base_ + 18432;
  float* MB1   = base_ + 34816;
  float* Z1c   = base_ + 51200;
  float* Z2c   = base_ + 59392;
  int*   flags = (int*)ws + clid * 64;
  float* WQW   = ws + WQK_BASE + (size_t)cg * 2080;   // Wq slice [4x260]
  float* WKW   = WQW + 1040;                          // Wk slice [4x260]

  // ---- resident weights / params ----
  for (int e = tid; e < 16 * 512; e += NTHR) {
    int k = e >> 4, c = e & 15;
    __hip_bfloat16 h = __float2bfloat16(W1[(size_t)k * H4 + ZC0 + c]);
    W1b[c * 520 + k] = *reinterpret_cast<ushort*>(&h);
  }
  for (int e = tid; e < 16 * 1024; e += NTHR) {
    int k = e >> 4, c = e & 15;
    __hip_bfloat16 h = __float2bfloat16(W2[(size_t)k * H4 + ZC0 + c]);
    W2b[c * 1032 + k] = *reinterpret_cast<ushort*>(&h);
  }
  // Wq/Wk own-col slices to ws (all same-cg blocks write identical values)
  for (int e = tid; e < 2048; e += NTHR) {
    int s = e >> 10, c = (e >> 8) & 3, k = e & 255;
    gstore((s ? WKW : WQW) + c * 260 + k, (s ? Wk : Wq)[k * HDIM + QC0 + c]);
  }
  if (tid < 16) { b1s[tid] = b1[ZC0 + tid]; b2s[tid] = b2[ZC0 + tid]; }
  if (tid < 4)  { bqS[tid] = bq[QC0 + tid]; bkS[tid] = bk[QC0 + tid]; }
  if (tid == 0) bbetaS[0] = bbeta[0];

  // ---- barrier primitives ----
  auto waitF = [&](int p) {
    if (tid < 64) {
      while (__hip_atomic_load(flags + tid, __ATOMIC_RELAXED, __HIP_MEMORY_SCOPE_AGENT) < p)
        __builtin_amdgcn_s_sleep(1);
    }
    __syncthreads();
  };
  auto sig = [&](int p) {
    asm volatile("s_waitcnt vmcnt(0)" ::: "memory");
    __syncthreads();
    if (tid == 0) __hip_atomic_store(flags + cg, p, __ATOMIC_RELAXED, __HIP_MEMORY_SCOPE_AGENT);
  };

  // ---- 8-row Z1 GEMM half over 256-k (wave w: 32 k) ----
  auto z1Half = [&](const float* Ap, int kwBase, float& a0, float& a1) {
    const int kb = w * 32;
#pragma unroll
    for (int kk = 0; kk < 32; kk += 8) {
      const int ka = kb + kk, kw = kwBase + kb + kk;
      float4 x0 = *(const float4*)&Ap[rl * 260 + ka];
      float4 x1 = *(const float4*)&Ap[rl * 260 + ka + 4];
      uint4 u0 = *(const uint4*)&W1b[cl * 520 + kw];
      uint4 u1 = *(const uint4*)&W1b[(cl + 8) * 520 + kw];
      fma8(a0, x0, x1, u0); fma8(a1, x0, x1, u1);
    }
  };
  auto redFinish = [&](float a0, float a1, float* dst, const float* bias, bool doRelu) {
    __syncthreads();                    // protect prior redS/Az readers
    redS[w * 132 + rl * 16 + cl] = a0;
    redS[w * 132 + rl * 16 + cl + 8] = a1;
    __syncthreads();
    if (tid < 64) {
      int r = tid >> 3, c0 = (tid & 7) * 2;
      float v0 = 0.f, v1 = 0.f;
#pragma unroll
      for (int w2 = 0; w2 < 8; ++w2) {
        v0 += redS[w2 * 132 + r * 16 + c0];
        v1 += redS[w2 * 132 + r * 16 + c0 + 1];
      }
      v0 += bias[c0]; v1 += bias[c0 + 1];
      if (doRelu) { v0 = fmaxf(v0, 0.f); v1 = fmaxf(v1, 0.f); }
      gstore2(dst + r * H4 + ZC0 + c0, v0, v1);
    }
  };

  // ---- 4-col projections (wave w = row w; 16 lanes per col) ----
  auto projQ = [&](const float* A /*plain global row*/, float* dst) {
    int col = lane >> 4, kp = lane & 15;
    const float* Wc = WQW + col * 260 + kp * 16;
    const float* Ak = A + kp * 16;
    float d = 0.f;
#pragma unroll
    for (int k4 = 0; k4 < 4; ++k4) {
      float4 a = *(const float4*)(Ak + 4 * k4);
      float4 wv = *(const float4*)(Wc + 4 * k4);
      d += a.x * wv.x + a.y * wv.y + a.z * wv.z + a.w * wv.w;
    }
    d += __shfl_xor(d, 1, 64); d += __shfl_xor(d, 2, 64);
    d += __shfl_xor(d, 4, 64); d += __shfl_xor(d, 8, 64);
    if (kp == 0) gstore(dst + col, d + bqS[col]);
  };
  auto projK_G = [&](const float* A /*LLC row (gload)*/, float* dst) {
    int col = lane >> 4, kp = lane & 15;
    const float* Wc = WKW + col * 260 + kp * 16;
    const float* Ak = A + kp * 16;
    float d = 0.f;
#pragma unroll
    for (int k2 = 0; k2 < 8; ++k2) {
      float2 a = gload2(Ak + 2 * k2);
      d += a.x * Wc[2 * k2] + a.y * Wc[2 * k2 + 1];
    }
    d += __shfl_xor(d, 1, 64); d += __shfl_xor(d, 2, 64);
    d += __shfl_xor(d, 4, 64); d += __shfl_xor(d, 8, 64);
    if (kp == 0) gstore(dst + col, d + bkS[col]);
  };
  auto projK_L = [&](const float* A /*LDS row*/, float* dst) {
    int col = lane >> 4, kp = lane & 15;
    const float* Wc = WKW + col * 260 + kp * 16;
    const float* Ak = A + kp * 16;
    float d = 0.f;
#pragma unroll
    for (int k4 = 0; k4 < 4; ++k4) {
      float4 a = *(const float4*)(Ak + 4 * k4);
      float4 wv = *(const float4*)(Wc + 4 * k4);
      d += a.x * wv.x + a.y * wv.y + a.z * wv.z + a.w * wv.w;
    }
    d += __shfl_xor(d, 1, 64); d += __shfl_xor(d, 2, 64);
    d += __shfl_xor(d, 4, 64); d += __shfl_xor(d, 8, 64);
    if (kp == 0) gstore(dst + col, d + bkS[col]);
  };

  // ================= t=0 init =================
  {
    if (tid < 256) {
      int e = cg * 256 + tid;          // 16384 floats over 64 blocks
      gstore(MB0 + e, 0.f);
      int r = e >> 11, s = (e >> 8) & 7, hd = e & 255;
      gstore(mem_out + ((size_t)(row0 + r) * NS + s) * HDIM + hd,
             Xp[(size_t)(row0 + r) * HDIM + hd]);
    }
    if (cg == 0 && tid < 64) gstore(probs_out + row0 * NS + tid, 0.f);
    {
      int r = tid >> 6, c4 = (tid & 63) * 4;   // prestage hloc = Xp[t=1]
      *(float4*)&hloc[r * 260 + c4] =
          *(const float4*)&Xp[((size_t)BATCH + row0 + r) * HDIM + c4];
    }
  }
  // drain weight-slice stores before local reads
  asm volatile("s_waitcnt vmcnt(0)" ::: "memory");
  __syncthreads();
  // S1a for t=1: q from Xp[1], k from Xp[0] broadcast to all slots
  {
    projQ(Xp + ((size_t)BATCH + row0 + w) * HDIM, QPRE + w * HDIM + QC0);
    int col = lane >> 4, kp = lane & 15;
    const float* Wc = WKW + col * 260 + kp * 16;
    const float* Ak = Xp + (size_t)(row0 + w) * HDIM + kp * 16;
    float d = 0.f;
#pragma unroll
    for (int k4 = 0; k4 < 4; ++k4) {
      float4 a = *(const float4*)(Ak + 4 * k4);
      float4 wv = *(const float4*)(Wc + 4 * k4);
      d += a.x * wv.x + a.y * wv.y + a.z * wv.z + a.w * wv.w;
    }
    d += __shfl_xor(d, 1, 64); d += __shfl_xor(d, 2, 64);
    d += __shfl_xor(d, 4, 64); d += __shfl_xor(d, 8, 64);
    if (kp == 0) {
      float vk = d + bkS[col];
#pragma unroll
      for (int s = 0; s < NS; ++s) gstore(KPRE + (w * 8 + s) * HDIM + QC0 + col, vk);
    }
  }
  int ph = 1;
  sig(ph);
  waitF(ph);

  // ================= time loop =================
  for (int t = 1; t < T_LEN; ++t) {
    const bool lastT = (t == T_LEN - 1);
    float* MbOld = ((t - 1) & 1) ? MB1 : MB0;
    float* MbNew = (t & 1) ? MB1 : MB0;
    const float* memPrev = mem_out + (size_t)(t - 1) * BATCH * NS * HDIM;
    float* memCur = mem_out + (size_t)t * BATCH * NS * HDIM;
    const float* probsPrev = probs_out + (size_t)(t - 1) * BATCH * NS;
    float* probsCur = probs_out + (size_t)t * BATCH * NS;

    // ---------- P1 ----------
    {
      // (1) q-LN (wave w = row w) -> Az
      const int hd0 = lane * 4;
      float2 v0 = gload2(QPRE + w * HDIM + hd0), v1 = gload2(QPRE + w * HDIM + hd0 + 2);
      float q[4] = {v0.x, v0.y, v1.x, v1.y};
      float s1 = q[0] + q[1] + q[2] + q[3];
      float s2 = q[0] * q[0] + q[1] * q[1] + q[2] * q[2] + q[3] * q[3];
#pragma unroll
      for (int m = 1; m < 64; m <<= 1) { s1 += __shfl_xor(s1, m, 64); s2 += __shfl_xor(s2, m, 64); }
      float mean = s1 * (1.f / 256.f);
      float inv = rsqrtf(s2 * (1.f / 256.f) - mean * mean + 1e-5f);
      float4 qs = *(const float4*)&lnqs[hd0];
      float4 qb = *(const float4*)&lnqb[hd0];
      *(float4*)&Az[w * 260 + hd0] = make_float4(
          (q[0] - mean) * inv * qs.x + qb.x, (q[1] - mean) * inv * qs.y + qb.y,
          (q[2] - mean) * inv * qs.z + qb.z, (q[3] - mean) * inv * qs.w + qb.w);
    }
    __syncthreads();
    {
      // (2) k-LN + beta: 64 krows x 8 threads
      const int kr = tid >> 3, u8 = tid & 7, rr = kr >> 3;
      const float* kp = KPRE + kr * HDIM + u8 * 32;
      float kv[32]; float s1 = 0.f, s2 = 0.f;
#pragma unroll
      for (int e = 0; e < 16; ++e) {
        float2 v = gload2(kp + 2 * e);
        kv[2 * e] = v.x; kv[2 * e + 1] = v.y;
        s1 += v.x + v.y; s2 += v.x * v.x + v.y * v.y;
      }
      s1 += __shfl_xor(s1, 1, 64); s1 += __shfl_xor(s1, 2, 64); s1 += __shfl_xor(s1, 4, 64);
      s2 += __shfl_xor(s2, 1, 64); s2 += __shfl_xor(s2, 2, 64); s2 += __shfl_xor(s2, 4, 64);
      float mean = s1 * (1.f / 256.f);
      float inv = rsqrtf(s2 * (1.f / 256.f) - mean * mean + 1e-5f);
      float dot = 0.f;
#pragma unroll
      for (int e = 0; e < 32; e += 4) {
        int hd = u8 * 32 + e;
        float4 ks4 = *(const float4*)&lnks[hd];
        float4 kb4 = *(const float4*)&lnkb[hd];
        float4 wb4 = *(const float4*)&Wbeta[hd];
        float kl0 = (kv[e] - mean) * inv * ks4.x + kb4.x;
        float kl1 = (kv[e + 1] - mean) * inv * ks4.y + kb4.y;
        float kl2 = (kv[e + 2] - mean) * inv * ks4.z + kb4.z;
        float kl3 = (kv[e + 3] - mean) * inv * ks4.w + kb4.w;
        dot += fmaxf(Az[rr * 260 + hd] + kl0, 0.f) * wb4.x;
        dot += fmaxf(Az[rr * 260 + hd + 1] + kl1, 0.f) * wb4.y;
        dot += fmaxf(Az[rr * 260 + hd + 2] + kl2, 0.f) * wb4.z;
        dot += fmaxf(Az[rr * 260 + hd + 3] + kl3, 0.f) * wb4.w;
      }
      dot += __shfl_xor(dot, 1, 64); dot += __shfl_xor(dot, 2, 64); dot += __shfl_xor(dot, 4, 64);
      if (u8 == 0) betaS[kr] = (dot + bbetaS[0]) * 0.0625f;
    }
    __syncthreads();
    // (3) softmax + mask + p/cp/rcp (8 threads)
    if (tid < 8) {
      int r = tid, b = row0 + r;
      float pp[8], pcp[8], run = 0.f;
#pragma unroll
      for (int s = 0; s < 8; s += 2) {
        float2 v = gload2(probsPrev + b * NS + s);
        pp[s] = v.x; pp[s + 1] = v.y;
      }
#pragma unroll
      for (int s = 0; s < 8; ++s) { run += pp[s]; pcp[s] = run; }
      float bmax = betaS[r * 8];
#pragma unroll
      for (int s = 1; s < 8; ++s) bmax = fmaxf(bmax, betaS[r * 8 + s]);
      float xm[8], ssum = 0.f;
#pragma unroll
      for (int s = 0; s < 8; ++s) {
        float mi = (s < 7) ? ((pcp[s + 1] < 1e-5f) ? 0.f : pcp[s + 1]) : 1.f;
        xm[s] = __expf(betaS[r * 8 + s] - bmax) * mi;
        ssum += fabsf(xm[s]);
      }
      float denom = fmaxf(ssum, 1e-12f);
      float run2 = 0.f, pn[8];
#pragma unroll
      for (int s = 0; s < 8; ++s) {
        pn[s] = xm[s] / denom; run2 += pn[s];
        cpS[r * 8 + s] = run2;
      }
      if (cg == r) {
#pragma unroll
        for (int s = 0; s < 8; s += 2) gstore2(probsCur + b * NS + s, pn[s], pn[s + 1]);
      }
      float run3 = 0.f;
#pragma unroll
      for (int s = 7; s >= 0; --s) { run3 += pn[s]; rcpS[r * 8 + s] = run3; }
    }
    __syncthreads();
    // (4) M-state owner update (own 4 cols, 8 rows x 8 slots)
    if (tid < 256) {
      int r = tid >> 5, s = (tid >> 2) & 7, c = tid & 3;
      int idx = (r * NS + s) * HDIM + QC0 + c;
      float rc = rcpS[r * 8 + s];
      float mo = gload(MbOld + idx);
      float cm = gload(memPrev + ((size_t)(row0 + r) * NS + s) * HDIM + QC0 + c);
      gstore(MbNew + idx, mo * (1.f - rc) + cm * rc);
    }
    // (5) stage Ast = blend(MbOld, memPrev) slot0 (hloc was prestaged)
    {
      const int r = tid >> 6, c4 = (tid & 63) * 4;
      float rc0 = rcpS[r * 8];
      float2 m0 = gload2(MbOld + (r * NS) * HDIM + c4);
      float2 m1 = gload2(MbOld + (r * NS) * HDIM + c4 + 2);
      float2 c0 = gload2(memPrev + ((size_t)(row0 + r) * NS) * HDIM + c4);
      float2 c1 = gload2(memPrev + ((size_t)(row0 + r) * NS) * HDIM + c4 + 2);
      *(float4*)&Ast[r * 260 + c4] = make_float4(
          m0.x * (1.f - rc0) + c0.x * rc0, m0.y * (1.f - rc0) + c0.y * rc0,
          m1.x * (1.f - rc0) + c1.x * rc0, m1.y * (1.f - rc0) + c1.y * rc0);
    }
    __syncthreads();
    {
      // Z1(0)
      float a0 = 0.f, a1 = 0.f;
      z1Half(Ast, 256, a0, a1);
      z1Half(hloc, 0, a0, a1);
      redFinish(a0, a1, Z1c, b1s, true);
    }
    ++ph; sig(ph);

    // ---------- cells ----------
    for (int ci = 0; ci < NS; ++ci) {
      const int phRdy = ph;
      // ---- Z2(ci): gather Z1 rows, 4 staged chunks through single Az ----
      {
        waitF(phRdy);
        const int r = tid >> 6, c4 = (tid & 63) * 4;
        const float* zr = Z1c + r * H4 + c4;
        float2 pf[8];
#pragma unroll
        for (int ch = 0; ch < 4; ++ch) {
          pf[ch * 2] = gload2(zr + ch * 256);
          pf[ch * 2 + 1] = gload2(zr + ch * 256 + 2);
        }
        float za0 = 0.f, za1 = 0.f;
#pragma unroll
        for (int ch = 0; ch < 4; ++ch) {
          if (ch) __syncthreads();     // prior chunk's readers done
          *(float4*)&Az[r * 260 + c4] =
              make_float4(pf[ch * 2].x, pf[ch * 2].y, pf[ch * 2 + 1].x, pf[ch * 2 + 1].y);
          __syncthreads();
          const int kb = w * 32, kw0 = ch * 256 + kb;
#pragma unroll
          for (int kk = 0; kk < 32; kk += 8) {
            float4 x0 = *(const float4*)&Az[rl * 260 + kb + kk];
            float4 x1 = *(const float4*)&Az[rl * 260 + kb + kk + 4];
            uint4 u0 = *(const uint4*)&W2b[cl * 1032 + kw0 + kk];
            uint4 u1 = *(const uint4*)&W2b[(cl + 8) * 1032 + kw0 + kk];
            fma8(za0, x0, x1, u0); fma8(za1, x0, x1, u1);
          }
        }
        redFinish(za0, za1, Z2c, b2s, false);
      }
      ++ph; sig(ph);   // signal A(ci)
      const int phA = ph;

      // ======== window A: overlap with peers' Z2 completion ========
      float4 hv = *(const float4*)&Ast[w * 260 + lane * 4];  // hi (slot ci, row w)
      __syncthreads();
      if (ci < 7) {
        // restage Ast = MbNew slot ci+1 (fully blended in P1)
        const int r = tid >> 6, c4 = (tid & 63) * 4;
        const float* src = MbNew + (r * NS + ci + 1) * HDIM + c4;
        float2 a = gload2(src), b = gload2(src + 2);
        *(float4*)&Ast[r * 260 + c4] = make_float4(a.x, a.y, b.x, b.y);
      } else if (!lastT) {
        // KPRE(s=6): memCur slot 6 visible (waited sigB(6) in Z2(7))
        projK_G(memCur + ((size_t)(row0 + w) * NS + 6) * HDIM,
                KPRE + (w * 8 + 6) * HDIM + QC0);
      }
      __syncthreads();
      float b0 = 0.f, b1v = 0.f;
      if (ci < 7) z1Half(Ast, 256, b0, b1v);   // Mn-half of Z1(ci+1)
      waitF(phA);

      // ---- H(ci): wave w = row w, 4 h-dims per lane ----
      {
        const float* z2r = Z2c + w * H4;
        const int hd0 = lane * 4;
        float2 cv0 = gload2(z2r + 768 + hd0), cv1 = gload2(z2r + 768 + hd0 + 2);
        float cc[4] = {cv0.x, cv0.y, cv1.x, cv1.y};
        float s1 = cc[0] + cc[1] + cc[2] + cc[3];
        float s2 = cc[0] * cc[0] + cc[1] * cc[1] + cc[2] * cc[2] + cc[3] * cc[3];
#pragma unroll
        for (int m = 1; m < 64; m <<= 1) { s1 += __shfl_xor(s1, m, 64); s2 += __shfl_xor(s2, m, 64); }
        float mean = s1 * (1.f / 256.f);
        float inv = rsqrtf(s2 * (1.f / 256.f) - mean * mean + 1e-5f);
        float g[12];
#pragma unroll
        for (int j = 0; j < 6; ++j) {
          float2 v = gload2(z2r + hd0 * 3 + 2 * j);
          g[2 * j] = v.x; g[2 * j + 1] = v.y;
        }
        float4 vi4 = *(const float4*)&hloc[w * 260 + hd0];
        float4 xp4 = *(const float4*)&Xp[((size_t)t * BATCH + row0 + w) * HDIM + hd0];
        float4 ls4 = *(const float4*)&lns[hd0];
        float4 lb4 = *(const float4*)&lnb[hd0];
        float viv[4] = {vi4.x, vi4.y, vi4.z, vi4.w};
        float xpv[4] = {xp4.x, xp4.y, xp4.z, xp4.w};
        float hivv[4] = {hv.x, hv.y, hv.z, hv.w};
        float lsv[4] = {ls4.x, ls4.y, ls4.z, ls4.w};
        float lbv[4] = {lb4.x, lb4.y, lb4.z, lb4.w};
        float cp = cpS[w * 8 + ci];
        float hn[4];
#pragma unroll
        for (int j = 0; j < 4; ++j) {
          float z0 = g[3 * j], z1v = g[3 * j + 1], z2g = g[3 * j + 2];
          float gm = fmaxf(z0, fmaxf(z1v, z2g));
          float e0 = __expf(z0 - gm), e1 = __expf(z1v - gm), e2 = __expf(z2g - gm);
          float act = ftanh((cc[j] - mean) * inv * lsv[j] + lbv[j]);
          float hc = (e0 * viv[j] + e1 * hivv[j] + e2 * act) * __builtin_amdgcn_rcpf(e0 + e1 + e2);
          hn[j] = xpv[j] * (1.f - cp) + hc * cp;
        }
        *(float4*)&hloc[w * 260 + hd0] = make_float4(hn[0], hn[1], hn[2], hn[3]);
        if (lane == cg) {   // lane*4 == QC0: owner writes 4 cols
          float* mp = memCur + ((size_t)(row0 + w) * NS + ci) * HDIM + QC0;
          gstore2(mp, hn[0], hn[1]);
          gstore2(mp + 2, hn[2], hn[3]);
        }
      }
      __syncthreads();
      if (ci < 7) {
        z1Half(hloc, 0, b0, b1v);   // h-half of Z1(ci+1)
        redFinish(b0, b1v, Z1c, b1s, true);
      } else if (!lastT) {
        // KPRE(s=7) from new h (LDS) — pre-sigB
        projK_L(&hloc[w * 260], KPRE + (w * 8 + 7) * HDIM + QC0);
      }
      ++ph; sig(ph);   // signal B(ci)

      // ======== window B: S1a(t+1) pieces (drained by NEXT signal) ========
      if (!lastT) {
        if (ci == 0) {
          projQ(Xp + ((size_t)(t + 1) * BATCH + row0 + w) * HDIM, QPRE + w * HDIM + QC0);
        } else if (ci <= 6) {
          const int s = ci - 1;   // memCur slot s visible (waited sigB(s) in Z2(ci))
          projK_G(memCur + ((size_t)(row0 + w) * NS + s) * HDIM,
                  KPRE + (w * 8 + s) * HDIM + QC0);
        } else {
          const int r = tid >> 6, c4 = (tid & 63) * 4;   // prestage hloc = Xp[t+1]
          *(float4*)&hloc[r * 260 + c4] =
              *(const float4*)&Xp[((size_t)(t + 1) * BATCH + row0 + r) * HDIM + c4];
        }
      }
    }
    waitF(ph);   // full barrier before next P1
  }
}

extern "C" void kernel_launch(void* const* d_in, const int* in_sizes, int n_in,
                              void* d_out, int out_size, void* d_ws, size_t ws_size,
                              hipStream_t stream) {
  (void)in_sizes; (void)n_in; (void)out_size; (void)ws_size;
  const float* X     = (const float*)d_in[0];
  const float* Wp    = (const float*)d_in[3];
  const float* bp    = (const float*)d_in[4];
  const float* lns   = (const float*)d_in[5];
  const float* lnb   = (const float*)d_in[6];
  const float* Wq    = (const float*)d_in[7];
  const float* bq    = (const float*)d_in[8];
  const float* lnqs  = (const float*)d_in[9];
  const float* lnqb  = (const float*)d_in[10];
  const float* Wk    = (const float*)d_in[11];
  const float* bk    = (const float*)d_in[12];
  const float* lnks  = (const float*)d_in[13];
  const float* lnkb  = (const float*)d_in[14];
  const float* Wbeta = (const float*)d_in[15];
  const float* bbeta = (const float*)d_in[16];
  const float* W1    = (const float*)d_in[17];
  const float* b1    = (const float*)d_in[18];
  const float* W2    = (const float*)d_in[19];
  const float* b2    = (const float*)d_in[20];

  float* out       = (float*)d_out;
  float* out_xp    = out;
  float* out_mem   = out + (size_t)T_LEN * BATCH * HDIM;
  float* out_probs = out_mem + (size_t)T_LEN * BATCH * NS * HDIM;
  float* ws        = (float*)d_ws;

  hipLaunchKernelGGL(init_ctrl, dim3(4), dim3(256), 0, stream, (int*)d_ws);
  hipLaunchKernelGGL(xp_kernel, dim3(1024), dim3(256), 0, stream, X, Wp, bp, lns, lnb, out_xp);
  hipLaunchKernelGGL(omr_main, dim3(512), dim3(NTHR), 0, stream,
                     out_xp, Wq, bq, lnqs, lnqb, Wk, bk, lnks, lnkb, Wbeta, bbeta,
                     W1, b1, W2, b2, lns, lnb, out_mem, out_probs, ws);
}

// Round 7
// 17581.503 us; speedup vs baseline: 1.1786x; 1.1786x over previous
//
#include <hip/hip_runtime.h>
#include <hip/hip_bf16.h>
#include <math.h>

#define T_LEN 128
#define BATCH 64
#define IND   512
#define HDIM  256
#define NS    8
#define H4    1024
#define NTHR  512
#define RPC   8        // rows per cluster (pipeline)
#define CSTRIDE 67584  // floats per cluster in ws

typedef unsigned long long ull;
typedef unsigned int uint;
typedef unsigned short ushort;

// ---- LLC-coherent accessors (bypass per-XCD L2): agent-scope relaxed atomics ----
__device__ __forceinline__ float gload(const float* p) {
  return __hip_atomic_load(p, __ATOMIC_RELAXED, __HIP_MEMORY_SCOPE_AGENT);
}
__device__ __forceinline__ float2 gload2(const float* p) {
  ull v = __hip_atomic_load((const ull*)p, __ATOMIC_RELAXED, __HIP_MEMORY_SCOPE_AGENT);
  return __builtin_bit_cast(float2, v);
}
__device__ __forceinline__ void gstore(float* p, float v) {
  __hip_atomic_store(p, v, __ATOMIC_RELAXED, __HIP_MEMORY_SCOPE_AGENT);
}
__device__ __forceinline__ void gstore2(float* p, float a, float b) {
  float2 t = make_float2(a, b);
  __hip_atomic_store((ull*)p, __builtin_bit_cast(ull, t), __ATOMIC_RELAXED, __HIP_MEMORY_SCOPE_AGENT);
}

__device__ __forceinline__ float2 bf2(uint u) {
  return make_float2(__uint_as_float(u << 16), __uint_as_float(u & 0xffff0000u));
}
// 8 bf16 weights vs 8 fp32 A values -> acc
__device__ __forceinline__ void fma8(float& acc, float4 x0, float4 x1, uint4 u) {
  float2 wA = bf2(u.x), wB = bf2(u.y), wC = bf2(u.z), wD = bf2(u.w);
  acc += x0.x * wA.x + x0.y * wA.y + x0.z * wB.x + x0.w * wB.y
       + x1.x * wC.x + x1.y * wC.y + x1.z * wD.x + x1.w * wD.y;
}

// fast tanh via hw exp
__device__ __forceinline__ float ftanh(float x) {
  float xc = fminf(fmaxf(x, -9.f), 9.f);
  float t = __expf(2.f * xc);
  return (t - 1.f) * __builtin_amdgcn_rcpf(t + 1.f);
}

extern "C" __global__ void init_ctrl(int* ctrl) {
  int t = blockIdx.x * blockDim.x + threadIdx.x;
  if (t < 1024) ctrl[t] = 0;
}

// ---------------- Xp = tanh(LN(X @ W_proj + b)) ----------------
extern "C" __global__ __launch_bounds__(256) void xp_kernel(
    const float* __restrict__ X, const float* __restrict__ Wp, const float* __restrict__ bp,
    const float* __restrict__ lns, const float* __restrict__ lnb, float* __restrict__ out_xp)
{
  __shared__ float Xs[8 * IND];
  __shared__ float Ys[8 * HDIM];
  const int tid = threadIdx.x;
  const size_t base = (size_t)blockIdx.x * 8;
  const float* Xb = X + base * IND;
  for (int e = tid; e < 8 * IND / 4; e += 256) ((float4*)Xs)[e] = ((const float4*)Xb)[e];
  __syncthreads();
  float acc[8];
#pragma unroll
  for (int r = 0; r < 8; ++r) acc[r] = 0.f;
  for (int k = 0; k < IND; ++k) {
    float wv = Wp[k * HDIM + tid];
#pragma unroll
    for (int r = 0; r < 8; ++r) acc[r] += Xs[r * IND + k] * wv;
  }
  float bpv = bp[tid];
#pragma unroll
  for (int r = 0; r < 8; ++r) Ys[r * HDIM + tid] = acc[r] + bpv;
  __syncthreads();
  int w = tid >> 6, lane = tid & 63;
  for (int rr = 0; rr < 2; ++rr) {
    int r = w * 2 + rr;
    float v[4]; float s1 = 0.f, s2 = 0.f;
#pragma unroll
    for (int e = 0; e < 4; ++e) { v[e] = Ys[r * HDIM + lane + 64 * e]; s1 += v[e]; s2 += v[e] * v[e]; }
#pragma unroll
    for (int off = 32; off > 0; off >>= 1) { s1 += __shfl_xor(s1, off, 64); s2 += __shfl_xor(s2, off, 64); }
    float m = s1 / 256.f;
    float iv = rsqrtf(s2 / 256.f - m * m + 1e-5f);
#pragma unroll
    for (int e = 0; e < 4; ++e) {
      int hd = lane + 64 * e;
      out_xp[(base + r) * HDIM + hd] = tanhf((v[e] - m) * iv * lns[hd] + lnb[hd]);
    }
  }
}

// ws float layout: [0..1023] int flags (cluster cl: ints [cl*64, cl*64+64)), 8 clusters;
// data base = 1024; per cluster cl (8 clusters of 8 rows), stride 67584:
//   QPRE +0 (2048), KPRE +2048 (16384), MB0 +18432 (16384), MB1 +34816 (16384),
//   Z1c +51200 (8192), Z2c +59392 (8192)

struct Pipe {
  float *QPRE, *KPRE, *MB0, *MB1, *Z1c, *Z2c;
  int* flags;
  float *hloc, *Ast, *cpS, *rcpS, *betaS;
  int row0;
};

// ---------------- main recurrent kernel: 8 clusters, 2 pipelines per block ----------------
extern "C" __global__ __launch_bounds__(NTHR, 1) void omr_main(
    const float* __restrict__ Xp,
    const float* __restrict__ Wq, const float* __restrict__ bq,
    const float* __restrict__ lnqs, const float* __restrict__ lnqb,
    const float* __restrict__ Wk, const float* __restrict__ bk,
    const float* __restrict__ lnks, const float* __restrict__ lnkb,
    const float* __restrict__ Wbeta, const float* __restrict__ bbeta,
    const float* __restrict__ W1, const float* __restrict__ b1,
    const float* __restrict__ W2, const float* __restrict__ b2,
    const float* __restrict__ lns, const float* __restrict__ lnb,
    float* __restrict__ mem_out, float* __restrict__ probs_out, float* __restrict__ ws)
{
  const int tid = threadIdx.x;
  const int sc = blockIdx.x >> 6;   // supercluster (4), pipes = clusters 2sc, 2sc+1
  const int cg = blockIdx.x & 63;   // column group within supercluster
  const int ZC0 = cg * 16;          // z1/z2 cols owned
  const int QC0 = cg * 4;           // q/k/h cols owned
  const int w = tid >> 6, lane = tid & 63;
  const int rl = lane >> 3, cl = lane & 7;   // 8x8 lane grid: rows (rl, rl+8), cols (cl, cl+8)

  // LDS ~139 KB; GEMM strides ≡ 4 mod 32 banks
  __shared__ ushort W1b[16 * 520];    // bf16 W1 col slice (shared by both pipes)
  __shared__ ushort W2b[16 * 1032];   // bf16 W2 col slice
  __shared__ float hloc0[RPC * 260], hloc1[RPC * 260];
  __shared__ float Ast0[RPC * 260], Ast1[RPC * 260];
  __shared__ float Az0[16 * 260], Az1[16 * 260];   // merged 16-row staging (dbuf)
  __shared__ float redS[8 * 260];                  // split-K partials (16x16 tile)
  __shared__ float LNS_[256], LNB_[256], LNKS_[256], LNKB_[256], Wbs[256];
  __shared__ float WQS[4 * 260], WKS[4 * 260];
  __shared__ float cp0[64], cp1[64], rcp0[64], rcp1[64], bet0[64], bet1[64];
  __shared__ float b1s[16], b2s[16], bqS[4], bkS[4], bbetaS[1];

  auto mkPipe = [&](int p, float* hl, float* as, float* cp, float* rcp, float* bet) {
    Pipe P;
    int clid = sc * 2 + p;
    float* base = ws + 1024 + (size_t)clid * CSTRIDE;
    P.QPRE = base; P.KPRE = base + 2048;
    P.MB0 = base + 18432; P.MB1 = base + 34816;
    P.Z1c = base + 51200; P.Z2c = base + 59392;
    P.flags = (int*)ws + clid * 64;
    P.hloc = hl; P.Ast = as; P.cpS = cp; P.rcpS = rcp; P.betaS = bet;
    P.row0 = clid * RPC;
    return P;
  };
  Pipe P0 = mkPipe(0, hloc0, Ast0, cp0, rcp0, bet0);
  Pipe P1 = mkPipe(1, hloc1, Ast1, cp1, rcp1, bet1);

  // ---- resident weights / params ----
  for (int e = tid; e < 16 * 512; e += NTHR) {
    int k = e >> 4, c = e & 15;
    __hip_bfloat16 h = __float2bfloat16(W1[(size_t)k * H4 + ZC0 + c]);
    W1b[c * 520 + k] = *reinterpret_cast<ushort*>(&h);
  }
  for (int e = tid; e < 16 * 1024; e += NTHR) {
    int k = e >> 4, c = e & 15;
    __hip_bfloat16 h = __float2bfloat16(W2[(size_t)k * H4 + ZC0 + c]);
    W2b[c * 1032 + k] = *reinterpret_cast<ushort*>(&h);
  }
  for (int e = tid; e < 2048; e += NTHR) {
    int s = e >> 10, c = (e >> 8) & 3, k = e & 255;
    (s ? WKS : WQS)[c * 260 + k] = (s ? Wk : Wq)[k * HDIM + QC0 + c];
  }
  if (tid < 256) {
    LNS_[tid] = lns[tid];  LNB_[tid] = lnb[tid];
    LNKS_[tid] = lnks[tid]; LNKB_[tid] = lnkb[tid];
    Wbs[tid] = Wbeta[tid];
  }
  if (tid < 16) { b1s[tid] = b1[ZC0 + tid]; b2s[tid] = b2[ZC0 + tid]; }
  if (tid < 4)  { bqS[tid] = bq[QC0 + tid]; bkS[tid] = bk[QC0 + tid]; }
  if (tid == 0) bbetaS[0] = bbeta[0];

  // ---- barrier primitives ----
  auto waitBoth = [&](int p) {
    if (tid < 64) {
      while (__hip_atomic_load(P0.flags + tid, __ATOMIC_RELAXED, __HIP_MEMORY_SCOPE_AGENT) < p) {}
    } else if (tid < 128) {
      while (__hip_atomic_load(P1.flags + (tid - 64), __ATOMIC_RELAXED, __HIP_MEMORY_SCOPE_AGENT) < p) {}
    }
    __syncthreads();
  };
  auto sigBoth = [&](int p) {
    asm volatile("s_waitcnt vmcnt(0)" ::: "memory");
    __syncthreads();
    if (tid == 0) __hip_atomic_store(P0.flags + cg, p, __ATOMIC_RELAXED, __HIP_MEMORY_SCOPE_AGENT);
    if (tid == 1) __hip_atomic_store(P1.flags + cg, p, __ATOMIC_RELAXED, __HIP_MEMORY_SCOPE_AGENT);
  };

  // ---- merged 16-row Z1 GEMM half: rows 0-7 from A0 (pipe0), 8-15 from A1 ----
  auto z1HalfM = [&](const float* A0, const float* A1, int kwBase,
                     float& a00, float& a01, float& a10, float& a11) {
    const int kb = w * 32;
#pragma unroll
    for (int kk = 0; kk < 32; kk += 8) {
      const int ka = kb + kk, kw = kwBase + kb + kk;
      float4 x0 = *(const float4*)&A0[rl * 260 + ka];
      float4 x1 = *(const float4*)&A0[rl * 260 + ka + 4];
      float4 y0 = *(const float4*)&A1[rl * 260 + ka];
      float4 y1 = *(const float4*)&A1[rl * 260 + ka + 4];
      uint4 u0 = *(const uint4*)&W1b[cl * 520 + kw];
      uint4 u1 = *(const uint4*)&W1b[(cl + 8) * 520 + kw];
      fma8(a00, x0, x1, u0); fma8(a01, x0, x1, u1);
      fma8(a10, y0, y1, u0); fma8(a11, y0, y1, u1);
    }
  };
  // merged reduce+store: rows 0-7 -> dst0, 8-15 -> dst1
  auto redFinishM = [&](float a00, float a01, float a10, float a11,
                        float* dst0, float* dst1, const float* bias, bool doRelu) {
    __syncthreads();                    // protect prior redS readers
    redS[w * 260 + rl * 16 + cl] = a00;
    redS[w * 260 + rl * 16 + cl + 8] = a01;
    redS[w * 260 + (rl + 8) * 16 + cl] = a10;
    redS[w * 260 + (rl + 8) * 16 + cl + 8] = a11;
    __syncthreads();
    if (tid < 128) {
      int r = tid >> 3, c0 = (tid & 7) * 2;
      float v0 = 0.f, v1 = 0.f;
#pragma unroll
      for (int w2 = 0; w2 < 8; ++w2) {
        v0 += redS[w2 * 260 + r * 16 + c0];
        v1 += redS[w2 * 260 + r * 16 + c0 + 1];
      }
      v0 += bias[c0]; v1 += bias[c0 + 1];
      if (doRelu) { v0 = fmaxf(v0, 0.f); v1 = fmaxf(v1, 0.f); }
      float* dst = (r < 8) ? dst0 : dst1;
      gstore2(dst + (r & 7) * H4 + ZC0 + c0, v0, v1);
    }
  };

  // ---- merged 4-col projections for both pipes (wave w = row w) ----
  auto projQ2 = [&](const float* A0, const float* A1, float* dst0, float* dst1) {
    int col = lane >> 4, kp = lane & 15;
    const float* Wc = WQS + col * 260 + kp * 16;
    const float* Ak0 = A0 + kp * 16;
    const float* Ak1 = A1 + kp * 16;
    float d0 = 0.f, d1 = 0.f;
#pragma unroll
    for (int k4 = 0; k4 < 4; ++k4) {
      float4 a0 = *(const float4*)(Ak0 + 4 * k4);
      float4 a1 = *(const float4*)(Ak1 + 4 * k4);
      float4 wv = make_float4(Wc[4 * k4], Wc[4 * k4 + 1], Wc[4 * k4 + 2], Wc[4 * k4 + 3]);
      d0 += a0.x * wv.x + a0.y * wv.y + a0.z * wv.z + a0.w * wv.w;
      d1 += a1.x * wv.x + a1.y * wv.y + a1.z * wv.z + a1.w * wv.w;
    }
    d0 += __shfl_xor(d0, 1, 64); d0 += __shfl_xor(d0, 2, 64);
    d0 += __shfl_xor(d0, 4, 64); d0 += __shfl_xor(d0, 8, 64);
    d1 += __shfl_xor(d1, 1, 64); d1 += __shfl_xor(d1, 2, 64);
    d1 += __shfl_xor(d1, 4, 64); d1 += __shfl_xor(d1, 8, 64);
    if (kp == 0) {
      gstore(dst0 + col, d0 + bqS[col]);
      gstore(dst1 + col, d1 + bqS[col]);
    }
  };
  auto projK_G2 = [&](const float* A0, const float* A1, float* dst0, float* dst1) {
    int col = lane >> 4, kp = lane & 15;
    const float* Wc = WKS + col * 260 + kp * 16;
    const float* Ak0 = A0 + kp * 16;
    const float* Ak1 = A1 + kp * 16;
    float v0[16], v1[16];
#pragma unroll
    for (int k2 = 0; k2 < 8; ++k2) {     // one merged burst: 16 gload2
      float2 a0 = gload2(Ak0 + 2 * k2);
      float2 a1 = gload2(Ak1 + 2 * k2);
      v0[2 * k2] = a0.x; v0[2 * k2 + 1] = a0.y;
      v1[2 * k2] = a1.x; v1[2 * k2 + 1] = a1.y;
    }
    float d0 = 0.f, d1 = 0.f;
#pragma unroll
    for (int e = 0; e < 16; ++e) { d0 += v0[e] * Wc[e]; d1 += v1[e] * Wc[e]; }
    d0 += __shfl_xor(d0, 1, 64); d0 += __shfl_xor(d0, 2, 64);
    d0 += __shfl_xor(d0, 4, 64); d0 += __shfl_xor(d0, 8, 64);
    d1 += __shfl_xor(d1, 1, 64); d1 += __shfl_xor(d1, 2, 64);
    d1 += __shfl_xor(d1, 4, 64); d1 += __shfl_xor(d1, 8, 64);
    if (kp == 0) {
      gstore(dst0 + col, d0 + bkS[col]);
      gstore(dst1 + col, d1 + bkS[col]);
    }
  };
  auto projK_L2 = [&](const float* A0, const float* A1, float* dst0, float* dst1) {
    int col = lane >> 4, kp = lane & 15;
    const float* Wc = WKS + col * 260 + kp * 16;
    const float* Ak0 = A0 + kp * 16;
    const float* Ak1 = A1 + kp * 16;
    float d0 = 0.f, d1 = 0.f;
#pragma unroll
    for (int k4 = 0; k4 < 4; ++k4) {
      float4 a0 = *(const float4*)(Ak0 + 4 * k4);
      float4 a1 = *(const float4*)(Ak1 + 4 * k4);
      float4 wv = make_float4(Wc[4 * k4], Wc[4 * k4 + 1], Wc[4 * k4 + 2], Wc[4 * k4 + 3]);
      d0 += a0.x * wv.x + a0.y * wv.y + a0.z * wv.z + a0.w * wv.w;
      d1 += a1.x * wv.x + a1.y * wv.y + a1.z * wv.z + a1.w * wv.w;
    }
    d0 += __shfl_xor(d0, 1, 64); d0 += __shfl_xor(d0, 2, 64);
    d0 += __shfl_xor(d0, 4, 64); d0 += __shfl_xor(d0, 8, 64);
    d1 += __shfl_xor(d1, 1, 64); d1 += __shfl_xor(d1, 2, 64);
    d1 += __shfl_xor(d1, 4, 64); d1 += __shfl_xor(d1, 8, 64);
    if (kp == 0) {
      gstore(dst0 + col, d0 + bkS[col]);
      gstore(dst1 + col, d1 + bkS[col]);
    }
  };

  // ---- t=0 init per pipe ----
  auto initPipe = [&](Pipe& P) {
    if (tid < 256) {
      int e = cg * 256 + tid;          // 16384 floats over 64 blocks
      gstore(P.MB0 + e, 0.f);
      int r = e >> 11, s = (e >> 8) & 7, hd = e & 255;
      gstore(mem_out + ((size_t)(P.row0 + r) * NS + s) * HDIM + hd,
             Xp[(size_t)(P.row0 + r) * HDIM + hd]);
    }
    if (cg == 0 && tid < 64) gstore(probs_out + P.row0 * NS + tid, 0.f);
    {
      int r = tid >> 6, c4 = (tid & 63) * 4;   // prestage hloc = Xp[t=1]
      *(float4*)&P.hloc[r * 260 + c4] =
          *(const float4*)&Xp[((size_t)BATCH + P.row0 + r) * HDIM + c4];
    }
  };
  // S1a for t=1: q from Xp[1], k from Xp[0] broadcast to all slots
  auto s1aInit = [&](Pipe& P) {
    int col = lane >> 4, kp = lane & 15;
    {
      const float* Wc = WQS + col * 260 + kp * 16;
      const float* Ak = Xp + ((size_t)BATCH + P.row0 + w) * HDIM + kp * 16;
      float d = 0.f;
#pragma unroll
      for (int k4 = 0; k4 < 4; ++k4) {
        float4 a = *(const float4*)(Ak + 4 * k4);
        d += a.x * Wc[4 * k4] + a.y * Wc[4 * k4 + 1] + a.z * Wc[4 * k4 + 2] + a.w * Wc[4 * k4 + 3];
      }
      d += __shfl_xor(d, 1, 64); d += __shfl_xor(d, 2, 64);
      d += __shfl_xor(d, 4, 64); d += __shfl_xor(d, 8, 64);
      if (kp == 0) gstore(P.QPRE + w * HDIM + QC0 + col, d + bqS[col]);
    }
    {
      const float* Wc = WKS + col * 260 + kp * 16;
      const float* Ak = Xp + (size_t)(P.row0 + w) * HDIM + kp * 16;
      float d = 0.f;
#pragma unroll
      for (int k4 = 0; k4 < 4; ++k4) {
        float4 a = *(const float4*)(Ak + 4 * k4);
        d += a.x * Wc[4 * k4] + a.y * Wc[4 * k4 + 1] + a.z * Wc[4 * k4 + 2] + a.w * Wc[4 * k4 + 3];
      }
      d += __shfl_xor(d, 1, 64); d += __shfl_xor(d, 2, 64);
      d += __shfl_xor(d, 4, 64); d += __shfl_xor(d, 8, 64);
      if (kp == 0) {
        float vk = d + bkS[col];
#pragma unroll
        for (int s = 0; s < NS; ++s) gstore(P.KPRE + (w * 8 + s) * HDIM + QC0 + col, vk);
      }
    }
  };

  // ---- merged H section: load both pipes' data in one burst, then compute ----
  auto hSecM = [&](int ci, int t, float* memCur, float4 hv0, float4 hv1) {
    const int hd0 = lane * 4;
    const float* z0r = P0.Z2c + w * H4;
    const float* z1r = P1.Z2c + w * H4;
    // ---- one merged load burst (both pipes) ----
    float2 c00 = gload2(z0r + 768 + hd0), c01 = gload2(z0r + 768 + hd0 + 2);
    float2 c10 = gload2(z1r + 768 + hd0), c11 = gload2(z1r + 768 + hd0 + 2);
    float g0[12], g1[12];
#pragma unroll
    for (int j = 0; j < 6; ++j) {
      float2 a = gload2(z0r + hd0 * 3 + 2 * j);
      float2 b = gload2(z1r + hd0 * 3 + 2 * j);
      g0[2 * j] = a.x; g0[2 * j + 1] = a.y;
      g1[2 * j] = b.x; g1[2 * j + 1] = b.y;
    }
    float4 ls4 = *(const float4*)&LNS_[hd0];
    float4 lb4 = *(const float4*)&LNB_[hd0];
    float lsv[4] = {ls4.x, ls4.y, ls4.z, ls4.w};
    float lbv[4] = {lb4.x, lb4.y, lb4.z, lb4.w};
    // ---- compute per pipe ----
#pragma unroll
    for (int p = 0; p < 2; ++p) {
      Pipe& P = p ? P1 : P0;
      float cc[4];
      if (p == 0) { cc[0] = c00.x; cc[1] = c00.y; cc[2] = c01.x; cc[3] = c01.y; }
      else        { cc[0] = c10.x; cc[1] = c10.y; cc[2] = c11.x; cc[3] = c11.y; }
      const float* g = p ? g1 : g0;
      float4 hv = p ? hv1 : hv0;
      float s1 = cc[0] + cc[1] + cc[2] + cc[3];
      float s2 = cc[0] * cc[0] + cc[1] * cc[1] + cc[2] * cc[2] + cc[3] * cc[3];
#pragma unroll
      for (int m = 1; m < 64; m <<= 1) { s1 += __shfl_xor(s1, m, 64); s2 += __shfl_xor(s2, m, 64); }
      float mean = s1 * (1.f / 256.f);
      float inv = rsqrtf(s2 * (1.f / 256.f) - mean * mean + 1e-5f);
      float4 vi4 = *(const float4*)&P.hloc[w * 260 + hd0];
      float4 xp4 = *(const float4*)&Xp[((size_t)t * BATCH + P.row0 + w) * HDIM + hd0];
      float viv[4] = {vi4.x, vi4.y, vi4.z, vi4.w};
      float xpv[4] = {xp4.x, xp4.y, xp4.z, xp4.w};
      float hivv[4] = {hv.x, hv.y, hv.z, hv.w};
      float cp = P.cpS[w * 8 + ci];
      float hn[4];
#pragma unroll
      for (int j = 0; j < 4; ++j) {
        float z0 = g[3 * j], z1v = g[3 * j + 1], z2g = g[3 * j + 2];
        float gm = fmaxf(z0, fmaxf(z1v, z2g));
        float e0 = __expf(z0 - gm), e1 = __expf(z1v - gm), e2 = __expf(z2g - gm);
        float act = ftanh((cc[j] - mean) * inv * lsv[j] + lbv[j]);
        float hc = (e0 * viv[j] + e1 * hivv[j] + e2 * act) * __builtin_amdgcn_rcpf(e0 + e1 + e2);
        hn[j] = xpv[j] * (1.f - cp) + hc * cp;
      }
      *(float4*)&P.hloc[w * 260 + hd0] = make_float4(hn[0], hn[1], hn[2], hn[3]);
      if (lane == cg) {
        float* mp = memCur + ((size_t)(P.row0 + w) * NS + ci) * HDIM + QC0;
        gstore2(mp, hn[0], hn[1]);
        gstore2(mp + 2, hn[2], hn[3]);
      }
    }
  };

  // ---- cell section 1: merged Z2(ci) for both pipes ----
  auto cellS1M = [&](int phRdy) {
    waitBoth(phRdy);
    // gather both pipes' z1 rows: thread -> row r16 (0..15), 8 cols at c8
    const int r16 = tid >> 5, c8 = (tid & 31) * 8;
    const float* zr = ((r16 < 8) ? P0.Z1c : P1.Z1c) + (r16 & 7) * H4 + c8;
    float2 pf[16];
#pragma unroll
    for (int ch = 0; ch < 4; ++ch) {
      const float* zq = zr + ch * 256;
      pf[ch * 4 + 0] = gload2(zq);     pf[ch * 4 + 1] = gload2(zq + 2);
      pf[ch * 4 + 2] = gload2(zq + 4); pf[ch * 4 + 3] = gload2(zq + 6);
    }
    *(float4*)&Az0[r16 * 260 + c8] = make_float4(pf[0].x, pf[0].y, pf[1].x, pf[1].y);
    *(float4*)&Az0[r16 * 260 + c8 + 4] = make_float4(pf[2].x, pf[2].y, pf[3].x, pf[3].y);
    __syncthreads();
    float za00 = 0.f, za01 = 0.f, za10 = 0.f, za11 = 0.f;
#pragma unroll
    for (int ch = 0; ch < 4; ++ch) {
      const float* buf = (ch & 1) ? Az1 : Az0;
      float* nbuf = (ch & 1) ? Az0 : Az1;
      const int kb = w * 32, kw0 = ch * 256 + kb;
#pragma unroll
      for (int kk = 0; kk < 32; kk += 8) {
        float4 x0 = *(const float4*)&buf[rl * 260 + kb + kk];
        float4 x1 = *(const float4*)&buf[rl * 260 + kb + kk + 4];
        float4 y0 = *(const float4*)&buf[(rl + 8) * 260 + kb + kk];
        float4 y1 = *(const float4*)&buf[(rl + 8) * 260 + kb + kk + 4];
        uint4 u0 = *(const uint4*)&W2b[cl * 1032 + kw0 + kk];
        uint4 u1 = *(const uint4*)&W2b[(cl + 8) * 1032 + kw0 + kk];
        fma8(za00, x0, x1, u0); fma8(za01, x0, x1, u1);
        fma8(za10, y0, y1, u0); fma8(za11, y0, y1, u1);
      }
      if (ch < 3) {
        int b4 = (ch + 1) * 4;
        *(float4*)&nbuf[r16 * 260 + c8] =
            make_float4(pf[b4].x, pf[b4].y, pf[b4 + 1].x, pf[b4 + 1].y);
        *(float4*)&nbuf[r16 * 260 + c8 + 4] =
            make_float4(pf[b4 + 2].x, pf[b4 + 2].y, pf[b4 + 3].x, pf[b4 + 3].y);
      }
      __syncthreads();
    }
    redFinishM(za00, za01, za10, za11, P0.Z2c, P1.Z2c, b2s, false);
  };

  // ---- cell section 2: window + H(ci) + merged Z1(ci+1) ----
  auto cellS2M = [&](int ci, int t, int phA, float* memCur) {
    const bool lastT = (t == T_LEN - 1);
    // hiv (Ast slot ci, row w) for both pipes before restage
    float4 hv0 = *(const float4*)&Ast0[w * 260 + lane * 4];
    float4 hv1 = *(const float4*)&Ast1[w * 260 + lane * 4];
    __syncthreads();
    if (ci < 7) {
      // restage both Ast = MbNew slot ci+1 (fully blended in P1)
      float* MbN0 = (t & 1) ? P0.MB1 : P0.MB0;
      float* MbN1 = (t & 1) ? P1.MB1 : P1.MB0;
      const int r16 = tid >> 5, c8 = (tid & 31) * 8, rr = r16 & 7;
      float* mb = (r16 < 8) ? MbN0 : MbN1;
      float* as = (r16 < 8) ? Ast0 : Ast1;
      const float* src = mb + (rr * NS + ci + 1) * HDIM + c8;
      float2 a0 = gload2(src), a1 = gload2(src + 2), a2 = gload2(src + 4), a3 = gload2(src + 6);
      *(float4*)&as[rr * 260 + c8] = make_float4(a0.x, a0.y, a1.x, a1.y);
      *(float4*)&as[rr * 260 + c8 + 4] = make_float4(a2.x, a2.y, a3.x, a3.y);
    } else if (!lastT) {
      // KPRE(s=6) from memCur slot 6 (visible: waited sigB(6) in cellS1(7))
      projK_G2(memCur + ((size_t)(P0.row0 + w) * NS + 6) * HDIM,
               memCur + ((size_t)(P1.row0 + w) * NS + 6) * HDIM,
               P0.KPRE + (w * 8 + 6) * HDIM + QC0,
               P1.KPRE + (w * 8 + 6) * HDIM + QC0);
    }
    __syncthreads();
    float b00 = 0.f, b01 = 0.f, b10 = 0.f, b11 = 0.f;
    if (ci < 7) z1HalfM(Ast0, Ast1, 256, b00, b01, b10, b11);   // Mn-half of Z1(ci+1)
    waitBoth(phA);
    hSecM(ci, t, memCur, hv0, hv1);
    __syncthreads();
    if (ci < 7) {
      z1HalfM(hloc0, hloc1, 0, b00, b01, b10, b11);   // h-half of Z1(ci+1)
      redFinishM(b00, b01, b10, b11, P0.Z1c, P1.Z1c, b1s, true);
    } else if (!lastT) {
      // KPRE(s=7) from new h (LDS) — pre-sigB
      projK_L2(&hloc0[w * 260], &hloc1[w * 260],
               P0.KPRE + (w * 8 + 7) * HDIM + QC0,
               P1.KPRE + (w * 8 + 7) * HDIM + QC0);
    }
  };

  // ---- B-window: S1a(t+1) pieces merged, drained by NEXT signal ----
  auto bWinM = [&](int ci, int t, float* memCur) {
    if (ci == 0) {
      projQ2(Xp + ((size_t)(t + 1) * BATCH + P0.row0 + w) * HDIM,
             Xp + ((size_t)(t + 1) * BATCH + P1.row0 + w) * HDIM,
             P0.QPRE + w * HDIM + QC0, P1.QPRE + w * HDIM + QC0);
    } else if (ci <= 6) {
      const int s = ci - 1;   // memCur slot s visible (waited sigB(s) in cellS1(ci))
      projK_G2(memCur + ((size_t)(P0.row0 + w) * NS + s) * HDIM,
               memCur + ((size_t)(P1.row0 + w) * NS + s) * HDIM,
               P0.KPRE + (w * 8 + s) * HDIM + QC0,
               P1.KPRE + (w * 8 + s) * HDIM + QC0);
    } else {
      // prestage hloc = Xp[t+1] for both pipes (merged 16-row pass)
      const int r16 = tid >> 5, c8 = (tid & 31) * 8, rr = r16 & 7;
      Pipe& P = (r16 < 8) ? P0 : P1;
      *(float4*)&P.hloc[rr * 260 + c8] =
          *(const float4*)&Xp[((size_t)(t + 1) * BATCH + P.row0 + rr) * HDIM + c8];
      *(float4*)&P.hloc[rr * 260 + c8 + 4] =
          *(const float4*)&Xp[((size_t)(t + 1) * BATCH + P.row0 + rr) * HDIM + c8 + 4];
    }
  };

  // ================= init + time loop =================
  __syncthreads();
  initPipe(P0); initPipe(P1);
  __syncthreads();
  s1aInit(P0); s1aInit(P1);
  int ph = 1;
  sigBoth(ph);
  waitBoth(ph);

  for (int t = 1; t < T_LEN; ++t) {
    const bool lastT = (t == T_LEN - 1);
    float* MbOld0 = ((t - 1) & 1) ? P0.MB1 : P0.MB0;
    float* MbOld1 = ((t - 1) & 1) ? P1.MB1 : P1.MB0;
    const float* memPrev = mem_out + (size_t)(t - 1) * BATCH * NS * HDIM;
    float* memCur = mem_out + (size_t)t * BATCH * NS * HDIM;
    const float* probsPrev = probs_out + (size_t)(t - 1) * BATCH * NS;
    float* probsCur = probs_out + (size_t)t * BATCH * NS;

    // ---------- P1 (merged pipes) ----------
    // (1) q-LN merged — safe pre-wait: QPRE(t) drained by producers' sigA(1..) of t-1,
    //     which our waitA(7) of t-1 already transitively guarantees (t=1: pre-loop barrier)
    {
      const int r16 = tid >> 5, hd0 = (tid & 31) * 8, row = r16 & 7;
      Pipe& P = (r16 < 8) ? P0 : P1;
      float q[8]; float s1 = 0.f, s2 = 0.f;
#pragma unroll
      for (int j = 0; j < 4; ++j) {
        float2 v = gload2(P.QPRE + row * HDIM + hd0 + 2 * j);
        q[2 * j] = v.x; q[2 * j + 1] = v.y;
        s1 += v.x + v.y; s2 += v.x * v.x + v.y * v.y;
      }
#pragma unroll
      for (int m = 1; m < 32; m <<= 1) { s1 += __shfl_xor(s1, m, 64); s2 += __shfl_xor(s2, m, 64); }
      float mean = s1 * (1.f / 256.f);
      float inv = rsqrtf(s2 * (1.f / 256.f) - mean * mean + 1e-5f);
#pragma unroll
      for (int j = 0; j < 8; ++j)
        Az0[r16 * 260 + hd0 + j] = (q[j] - mean) * inv * lnqs[hd0 + j] + lnqb[hd0 + j];
    }
    // wait for all blocks' B(7) of t-1 (KPRE fresh) — hidden under q-LN above
    waitBoth(ph);
    {
      // (2) k-LN + beta merged: 128 krows x 4 threads (one 64-float burst)
      const int kr128 = tid >> 2, u4 = tid & 3;
      Pipe& P = (kr128 < 64) ? P0 : P1;
      const int kr = kr128 & 63;
      const int rr16 = (kr >> 3) + ((kr128 < 64) ? 0 : 8);
      const float* kp = P.KPRE + kr * HDIM + u4 * 64;
      float kv[64]; float s1 = 0.f, s2 = 0.f;
#pragma unroll
      for (int e = 0; e < 32; ++e) {
        float2 v = gload2(kp + 2 * e);
        kv[2 * e] = v.x; kv[2 * e + 1] = v.y;
        s1 += v.x + v.y; s2 += v.x * v.x + v.y * v.y;
      }
      s1 += __shfl_xor(s1, 1, 64); s1 += __shfl_xor(s1, 2, 64);
      s2 += __shfl_xor(s2, 1, 64); s2 += __shfl_xor(s2, 2, 64);
      float mean = s1 * (1.f / 256.f);
      float inv = rsqrtf(s2 * (1.f / 256.f) - mean * mean + 1e-5f);
      float dot = 0.f;
#pragma unroll
      for (int e = 0; e < 64; ++e) {
        int hd = u4 * 64 + e;
        float kl = (kv[e] - mean) * inv * LNKS_[hd] + LNKB_[hd];
        float rv = fmaxf(Az0[rr16 * 260 + hd] + kl, 0.f);
        dot += rv * Wbs[hd];
      }
      dot += __shfl_xor(dot, 1, 64); dot += __shfl_xor(dot, 2, 64);
      if (u4 == 0) P.betaS[kr] = (dot + bbetaS[0]) * 0.0625f;
    }
    __syncthreads();
    // (3) softmax + mask + p/cp/rcp (16 threads: 2 pipes x 8 rows)
    if (tid < 16) {
      Pipe& P = (tid < 8) ? P0 : P1;
      int r = tid & 7, b = P.row0 + r;
      float pp[8], pcp[8], run = 0.f;
#pragma unroll
      for (int s = 0; s < 8; s += 2) {
        float2 v = gload2(probsPrev + b * NS + s);
        pp[s] = v.x; pp[s + 1] = v.y;
      }
#pragma unroll
      for (int s = 0; s < 8; ++s) { run += pp[s]; pcp[s] = run; }
      float bmax = P.betaS[r * 8];
#pragma unroll
      for (int s = 1; s < 8; ++s) bmax = fmaxf(bmax, P.betaS[r * 8 + s]);
      float xm[8], ssum = 0.f;
#pragma unroll
      for (int s = 0; s < 8; ++s) {
        float mi = (s < 7) ? ((pcp[s + 1] < 1e-5f) ? 0.f : pcp[s + 1]) : 1.f;
        xm[s] = __expf(P.betaS[r * 8 + s] - bmax) * mi;
        ssum += fabsf(xm[s]);
      }
      float denom = fmaxf(ssum, 1e-12f);
      float run2 = 0.f, pn[8];
#pragma unroll
      for (int s = 0; s < 8; ++s) {
        pn[s] = xm[s] / denom; run2 += pn[s];
        P.cpS[r * 8 + s] = run2;
      }
      if (cg == tid) {   // 16 distinct writer blocks
#pragma unroll
        for (int s = 0; s < 8; s += 2) gstore2(probsCur + b * NS + s, pn[s], pn[s + 1]);
      }
      float run3 = 0.f;
#pragma unroll
      for (int s = 7; s >= 0; --s) { run3 += pn[s]; P.rcpS[r * 8 + s] = run3; }
    }
    __syncthreads();
    // (4) M-state owner update merged (2 pipes x 8r x 8s x 4c = 512 threads)
    {
      Pipe& P = (tid < 256) ? P0 : P1;
      float* MbOld = (tid < 256) ? MbOld0 : MbOld1;
      float* MbNew = (t & 1) ? P.MB1 : P.MB0;
      int e = tid & 255;
      int r = e >> 5, s = (e >> 2) & 7, c = e & 3;
      int idx = (r * NS + s) * HDIM + QC0 + c;
      float rc = P.rcpS[r * 8 + s];
      float mo = gload(MbOld + idx);
      float cm = gload(memPrev + ((size_t)(P.row0 + r) * NS + s) * HDIM + QC0 + c);
      gstore(MbNew + idx, mo * (1.f - rc) + cm * rc);
    }
    // (5) stage Ast = blend(MbOld, memPrev) slot0 merged (16 rows x 32 thr)
    {
      const int r16 = tid >> 5, c8 = (tid & 31) * 8, rr = r16 & 7;
      Pipe& P = (r16 < 8) ? P0 : P1;
      float* MbOld = (r16 < 8) ? MbOld0 : MbOld1;
      float rc0 = P.rcpS[rr * 8];
      const float* mo = MbOld + (rr * NS) * HDIM + c8;
      const float* cm = memPrev + ((size_t)(P.row0 + rr) * NS) * HDIM + c8;
      float2 m0 = gload2(mo), m1 = gload2(mo + 2), m2 = gload2(mo + 4), m3 = gload2(mo + 6);
      float2 c0 = gload2(cm), c1 = gload2(cm + 2), c2 = gload2(cm + 4), c3 = gload2(cm + 6);
      float* as = (r16 < 8) ? Ast0 : Ast1;
      *(float4*)&as[rr * 260 + c8] = make_float4(
          m0.x * (1.f - rc0) + c0.x * rc0, m0.y * (1.f - rc0) + c0.y * rc0,
          m1.x * (1.f - rc0) + c1.x * rc0, m1.y * (1.f - rc0) + c1.y * rc0);
      *(float4*)&as[rr * 260 + c8 + 4] = make_float4(
          m2.x * (1.f - rc0) + c2.x * rc0, m2.y * (1.f - rc0) + c2.y * rc0,
          m3.x * (1.f - rc0) + c3.x * rc0, m3.y * (1.f - rc0) + c3.y * rc0);
    }
    __syncthreads();
    {
      // merged Z1(0): Mn-half (Ast) + h-half (hloc)
      float a00 = 0.f, a01 = 0.f, a10 = 0.f, a11 = 0.f;
      z1HalfM(Ast0, Ast1, 256, a00, a01, a10, a11);
      z1HalfM(hloc0, hloc1, 0, a00, a01, a10, a11);
      redFinishM(a00, a01, a10, a11, P0.Z1c, P1.Z1c, b1s, true);
    }
    ++ph; sigBoth(ph);

    // ---------- cells ----------
    for (int ci = 0; ci < NS; ++ci) {
      const int phRdy = ph;
      cellS1M(phRdy);
      ++ph; sigBoth(ph);
      cellS2M(ci, t, ph, memCur);
      ++ph; sigBoth(ph);
      if (!lastT) bWinM(ci, t, memCur);
    }
    // NOTE: no end-of-loop wait — P1's q-LN runs pre-wait; waitBoth(ph) happens
    // right after q-LN at the top of the next iteration.
  }
}

extern "C" void kernel_launch(void* const* d_in, const int* in_sizes, int n_in,
                              void* d_out, int out_size, void* d_ws, size_t ws_size,
                              hipStream_t stream) {
  (void)in_sizes; (void)n_in; (void)out_size; (void)ws_size;
  const float* X     = (const float*)d_in[0];
  const float* Wp    = (const float*)d_in[3];
  const float* bp    = (const float*)d_in[4];
  const float* lns   = (const float*)d_in[5];
  const float* lnb   = (const float*)d_in[6];
  const float* Wq    = (const float*)d_in[7];
  const float* bq    = (const float*)d_in[8];
  const float* lnqs  = (const float*)d_in[9];
  const float* lnqb  = (const float*)d_in[10];
  const float* Wk    = (const float*)d_in[11];
  const float* bk    = (const float*)d_in[12];
  const float* lnks  = (const float*)d_in[13];
  const float* lnkb  = (const float*)d_in[14];
  const float* Wbeta = (const float*)d_in[15];
  const float* bbeta = (const float*)d_in[16];
  const float* W1    = (const float*)d_in[17];
  const float* b1    = (const float*)d_in[18];
  const float* W2    = (const float*)d_in[19];
  const float* b2    = (const float*)d_in[20];

  float* out       = (float*)d_out;
  float* out_xp    = out;
  float* out_mem   = out + (size_t)T_LEN * BATCH * HDIM;
  float* out_probs = out_mem + (size_t)T_LEN * BATCH * NS * HDIM;
  float* ws        = (float*)d_ws;

  hipLaunchKernelGGL(init_ctrl, dim3(4), dim3(256), 0, stream, (int*)d_ws);
  hipLaunchKernelGGL(xp_kernel, dim3(1024), dim3(256), 0, stream, X, Wp, bp, lns, lnb, out_xp);
  hipLaunchKernelGGL(omr_main, dim3(256), dim3(NTHR), 0, stream,
                     out_xp, Wq, bq, lnqs, lnqb, Wk, bk, lnks, lnkb, Wbeta, bbeta,
                     W1, b1, W2, b2, lns, lnb, out_mem, out_probs, ws);
}

// Round 8
// 13237.920 us; speedup vs baseline: 1.5653x; 1.3281x over previous
//
#include <hip/hip_runtime.h>
#include <hip/hip_bf16.h>
#include <math.h>

#define T_LEN 128
#define BATCH 64
#define IND   512
#define HDIM  256
#define NS    8
#define H4    1024
#define NTHR  512
#define RPC   8        // rows per cluster (pipeline)
#define CSTRIDE 67584  // floats per cluster in ws

typedef unsigned long long ull;
typedef unsigned int uint;
typedef unsigned short ushort;
typedef _Float16 f16x2 __attribute__((ext_vector_type(2)));

// ---- LLC-coherent accessors (bypass per-XCD L2): agent-scope relaxed atomics ----
__device__ __forceinline__ float gload(const float* p) {
  return __hip_atomic_load(p, __ATOMIC_RELAXED, __HIP_MEMORY_SCOPE_AGENT);
}
__device__ __forceinline__ float2 gload2(const float* p) {
  ull v = __hip_atomic_load((const ull*)p, __ATOMIC_RELAXED, __HIP_MEMORY_SCOPE_AGENT);
  return __builtin_bit_cast(float2, v);
}
__device__ __forceinline__ void gstore(float* p, float v) {
  __hip_atomic_store(p, v, __ATOMIC_RELAXED, __HIP_MEMORY_SCOPE_AGENT);
}
__device__ __forceinline__ void gstore2(float* p, float a, float b) {
  float2 t = make_float2(a, b);
  __hip_atomic_store((ull*)p, __builtin_bit_cast(ull, t), __ATOMIC_RELAXED, __HIP_MEMORY_SCOPE_AGENT);
}
__device__ __forceinline__ void gstoreu(uint* p, uint v) {
  __hip_atomic_store(p, v, __ATOMIC_RELAXED, __HIP_MEMORY_SCOPE_AGENT);
}
__device__ __forceinline__ uint2 gloadu2(const uint* p) {
  ull v = __hip_atomic_load((const ull*)p, __ATOMIC_RELAXED, __HIP_MEMORY_SCOPE_AGENT);
  return __builtin_bit_cast(uint2, v);
}

// ---- f16 pack/unpack + dot ----
__device__ __forceinline__ uint pack2(float a, float b) {
  f16x2 v; v.x = (_Float16)a; v.y = (_Float16)b;
  return __builtin_bit_cast(uint, v);
}
__device__ __forceinline__ float2 unpack2(uint u) {
  f16x2 v = __builtin_bit_cast(f16x2, u);
  return make_float2((float)v.x, (float)v.y);
}
__device__ __forceinline__ float dot2u(float acc, uint a, uint b) {
  f16x2 av = __builtin_bit_cast(f16x2, a), bv = __builtin_bit_cast(f16x2, b);
#if __has_builtin(__builtin_amdgcn_fdot2)
  return __builtin_amdgcn_fdot2(av, bv, acc, false);
#else
  return acc + (float)av.x * (float)bv.x + (float)av.y * (float)bv.y;
#endif
}
__device__ __forceinline__ float dot8(float acc, uint4 a, uint4 w) {
  acc = dot2u(acc, a.x, w.x);
  acc = dot2u(acc, a.y, w.y);
  acc = dot2u(acc, a.z, w.z);
  acc = dot2u(acc, a.w, w.w);
  return acc;
}

// fast tanh via hw exp
__device__ __forceinline__ float ftanh(float x) {
  float xc = fminf(fmaxf(x, -9.f), 9.f);
  float t = __expf(2.f * xc);
  return (t - 1.f) * __builtin_amdgcn_rcpf(t + 1.f);
}

extern "C" __global__ void init_ctrl(int* ctrl) {
  int t = blockIdx.x * blockDim.x + threadIdx.x;
  if (t < 1024) ctrl[t] = 0;
}

// ---------------- Xp = tanh(LN(X @ W_proj + b)) ----------------
extern "C" __global__ __launch_bounds__(256) void xp_kernel(
    const float* __restrict__ X, const float* __restrict__ Wp, const float* __restrict__ bp,
    const float* __restrict__ lns, const float* __restrict__ lnb, float* __restrict__ out_xp)
{
  __shared__ float Xs[8 * IND];
  __shared__ float Ys[8 * HDIM];
  const int tid = threadIdx.x;
  const size_t base = (size_t)blockIdx.x * 8;
  const float* Xb = X + base * IND;
  for (int e = tid; e < 8 * IND / 4; e += 256) ((float4*)Xs)[e] = ((const float4*)Xb)[e];
  __syncthreads();
  float acc[8];
#pragma unroll
  for (int r = 0; r < 8; ++r) acc[r] = 0.f;
  for (int k = 0; k < IND; ++k) {
    float wv = Wp[k * HDIM + tid];
#pragma unroll
    for (int r = 0; r < 8; ++r) acc[r] += Xs[r * IND + k] * wv;
  }
  float bpv = bp[tid];
#pragma unroll
  for (int r = 0; r < 8; ++r) Ys[r * HDIM + tid] = acc[r] + bpv;
  __syncthreads();
  int w = tid >> 6, lane = tid & 63;
  for (int rr = 0; rr < 2; ++rr) {
    int r = w * 2 + rr;
    float v[4]; float s1 = 0.f, s2 = 0.f;
#pragma unroll
    for (int e = 0; e < 4; ++e) { v[e] = Ys[r * HDIM + lane + 64 * e]; s1 += v[e]; s2 += v[e] * v[e]; }
#pragma unroll
    for (int off = 32; off > 0; off >>= 1) { s1 += __shfl_xor(s1, off, 64); s2 += __shfl_xor(s2, off, 64); }
    float m = s1 / 256.f;
    float iv = rsqrtf(s2 / 256.f - m * m + 1e-5f);
#pragma unroll
    for (int e = 0; e < 4; ++e) {
      int hd = lane + 64 * e;
      out_xp[(base + r) * HDIM + hd] = tanhf((v[e] - m) * iv * lns[hd] + lnb[hd]);
    }
  }
}

// ws float layout: [0..1023] int flags (cluster cl: ints [cl*64, cl*64+64)), 8 clusters;
// data base = 1024; per cluster cl (8 clusters of 8 rows), stride 67584:
//   QPRE +0 (2048), KPRE +2048 (16384), MB0 +18432 (16384), MB1 +34816 (16384),
//   Z1c +51200 (f16x2: 8*512 uints), Z2c +59392 (f16x2: 8*512 uints)

struct Pipe {
  float *QPRE, *KPRE, *MB0, *MB1;
  uint *Z1u, *Z2u;
  int* flags;
  uint *hloc, *Ast;
  float *cpS, *rcpS, *betaS;
  int row0;
};

// ---------------- main recurrent kernel: 8 clusters, 2 pipelines per block ----------------
extern "C" __global__ __launch_bounds__(NTHR, 1) void omr_main(
    const float* __restrict__ Xp,
    const float* __restrict__ Wq, const float* __restrict__ bq,
    const float* __restrict__ lnqs, const float* __restrict__ lnqb,
    const float* __restrict__ Wk, const float* __restrict__ bk,
    const float* __restrict__ lnks, const float* __restrict__ lnkb,
    const float* __restrict__ Wbeta, const float* __restrict__ bbeta,
    const float* __restrict__ W1, const float* __restrict__ b1,
    const float* __restrict__ W2, const float* __restrict__ b2,
    const float* __restrict__ lns, const float* __restrict__ lnb,
    float* __restrict__ mem_out, float* __restrict__ probs_out, float* __restrict__ ws)
{
  const int tid = threadIdx.x;
  const int sc = blockIdx.x >> 6;   // supercluster (4), pipes = clusters 2sc, 2sc+1
  const int cg = blockIdx.x & 63;   // column group within supercluster
  const int ZC0 = cg * 16;          // z1/z2 cols owned
  const int QC0 = cg * 4;           // q/k/h cols owned
  const int w = tid >> 6, lane = tid & 63;
  const int rl = lane >> 3, cl = lane & 7;   // 8x8 lane grid: rows (rl, rl+8), cols (cl, cl+8)

  // LDS ~107 KB; GEMM strides ≡ 4 mod 32 banks (in 4B words)
  __shared__ uint W1b[16 * 260];     // f16x2 W1 col slice (256 pairs + pad)
  __shared__ uint W2b[16 * 516];     // f16x2 W2 col slice (512 pairs + pad)
  __shared__ uint hloc0[RPC * 132], hloc1[RPC * 132];  // f16x2 rows
  __shared__ uint Ast0[RPC * 132], Ast1[RPC * 132];
  __shared__ uint Az0[16 * 132], Az1[16 * 132];        // merged staging (dbuf)
  __shared__ float redS[8 * 260];                      // split-K partials (16x16)
  __shared__ float LNS_[256], LNB_[256], LNKS_[256], LNKB_[256], Wbs[256];
  __shared__ float WQS[4 * 260], WKS[4 * 260];
  __shared__ float cp0[64], cp1[64], rcp0[64], rcp1[64], bet0[64], bet1[64];
  __shared__ float b1s[16], b2s[16], bqS[4], bkS[4], bbetaS[1];

  auto mkPipe = [&](int p, uint* hl, uint* as, float* cp, float* rcp, float* bet) {
    Pipe P;
    int clid = sc * 2 + p;
    float* base = ws + 1024 + (size_t)clid * CSTRIDE;
    P.QPRE = base; P.KPRE = base + 2048;
    P.MB0 = base + 18432; P.MB1 = base + 34816;
    P.Z1u = (uint*)(base + 51200); P.Z2u = (uint*)(base + 59392);
    P.flags = (int*)ws + clid * 64;
    P.hloc = hl; P.Ast = as; P.cpS = cp; P.rcpS = rcp; P.betaS = bet;
    P.row0 = clid * RPC;
    return P;
  };
  Pipe P0 = mkPipe(0, hloc0, Ast0, cp0, rcp0, bet0);
  Pipe P1 = mkPipe(1, hloc1, Ast1, cp1, rcp1, bet1);

  // ---- resident weights / params (f16 pairs along K) ----
  for (int e = tid; e < 16 * 256; e += NTHR) {
    int kp = e >> 4, c = e & 15;
    W1b[c * 260 + kp] = pack2(W1[(size_t)(2 * kp) * H4 + ZC0 + c],
                              W1[(size_t)(2 * kp + 1) * H4 + ZC0 + c]);
  }
  for (int e = tid; e < 16 * 512; e += NTHR) {
    int kp = e >> 4, c = e & 15;
    W2b[c * 516 + kp] = pack2(W2[(size_t)(2 * kp) * H4 + ZC0 + c],
                              W2[(size_t)(2 * kp + 1) * H4 + ZC0 + c]);
  }
  for (int e = tid; e < 2048; e += NTHR) {
    int s = e >> 10, c = (e >> 8) & 3, k = e & 255;
    (s ? WKS : WQS)[c * 260 + k] = (s ? Wk : Wq)[k * HDIM + QC0 + c];
  }
  if (tid < 256) {
    LNS_[tid] = lns[tid];  LNB_[tid] = lnb[tid];
    LNKS_[tid] = lnks[tid]; LNKB_[tid] = lnkb[tid];
    Wbs[tid] = Wbeta[tid];
  }
  if (tid < 16) { b1s[tid] = b1[ZC0 + tid]; b2s[tid] = b2[ZC0 + tid]; }
  if (tid < 4)  { bqS[tid] = bq[QC0 + tid]; bkS[tid] = bk[QC0 + tid]; }
  if (tid == 0) bbetaS[0] = bbeta[0];

  // ---- barrier primitives ----
  auto waitBoth = [&](int p) {
    if (tid < 64) {
      while (__hip_atomic_load(P0.flags + tid, __ATOMIC_RELAXED, __HIP_MEMORY_SCOPE_AGENT) < p) {}
    } else if (tid < 128) {
      while (__hip_atomic_load(P1.flags + (tid - 64), __ATOMIC_RELAXED, __HIP_MEMORY_SCOPE_AGENT) < p) {}
    }
    __syncthreads();
  };
  auto sigBoth = [&](int p) {
    asm volatile("s_waitcnt vmcnt(0)" ::: "memory");
    __syncthreads();
    if (tid == 0) __hip_atomic_store(P0.flags + cg, p, __ATOMIC_RELAXED, __HIP_MEMORY_SCOPE_AGENT);
    if (tid == 1) __hip_atomic_store(P1.flags + cg, p, __ATOMIC_RELAXED, __HIP_MEMORY_SCOPE_AGENT);
  };

  // ---- merged 16-row Z1 GEMM half (f16 dot): rows 0-7 from A0, 8-15 from A1 ----
  // kwBaseP in k-PAIR units (0 or 128)
  auto z1HalfM = [&](const uint* A0, const uint* A1, int kwBaseP,
                     float& a00, float& a01, float& a10, float& a11) {
    const int kbp = w * 16;
#pragma unroll
    for (int kk = 0; kk < 16; kk += 4) {
      uint4 x = *(const uint4*)&A0[rl * 132 + kbp + kk];
      uint4 y = *(const uint4*)&A1[rl * 132 + kbp + kk];
      uint4 u0 = *(const uint4*)&W1b[cl * 260 + kwBaseP + kbp + kk];
      uint4 u1 = *(const uint4*)&W1b[(cl + 8) * 260 + kwBaseP + kbp + kk];
      a00 = dot8(a00, x, u0); a01 = dot8(a01, x, u1);
      a10 = dot8(a10, y, u0); a11 = dot8(a11, y, u1);
    }
  };
  // merged reduce+store: rows 0-7 -> dst0, 8-15 -> dst1 (f16x2-packed dst rows of 512 uints)
  auto redFinishM = [&](float a00, float a01, float a10, float a11,
                        uint* dst0, uint* dst1, const float* bias, bool doRelu) {
    __syncthreads();                    // protect prior redS readers
    redS[w * 260 + rl * 16 + cl] = a00;
    redS[w * 260 + rl * 16 + cl + 8] = a01;
    redS[w * 260 + (rl + 8) * 16 + cl] = a10;
    redS[w * 260 + (rl + 8) * 16 + cl + 8] = a11;
    __syncthreads();
    if (tid < 128) {
      int r = tid >> 3, c0 = (tid & 7) * 2;
      float v0 = 0.f, v1 = 0.f;
#pragma unroll
      for (int w2 = 0; w2 < 8; ++w2) {
        v0 += redS[w2 * 260 + r * 16 + c0];
        v1 += redS[w2 * 260 + r * 16 + c0 + 1];
      }
      v0 += bias[c0]; v1 += bias[c0 + 1];
      if (doRelu) { v0 = fmaxf(v0, 0.f); v1 = fmaxf(v1, 0.f); }
      uint* dst = (r < 8) ? dst0 : dst1;
      gstoreu(dst + (r & 7) * 512 + (ZC0 + c0) / 2, pack2(v0, v1));
    }
  };

  // ---- merged 4-col projections for both pipes (wave w = row w) ----
  auto projQ2 = [&](const float* A0, const float* A1, float* dst0, float* dst1) {
    int col = lane >> 4, kp = lane & 15;
    const float* Wc = WQS + col * 260 + kp * 16;
    const float* Ak0 = A0 + kp * 16;
    const float* Ak1 = A1 + kp * 16;
    float d0 = 0.f, d1 = 0.f;
#pragma unroll
    for (int k4 = 0; k4 < 4; ++k4) {
      float4 a0 = *(const float4*)(Ak0 + 4 * k4);
      float4 a1 = *(const float4*)(Ak1 + 4 * k4);
      float4 wv = make_float4(Wc[4 * k4], Wc[4 * k4 + 1], Wc[4 * k4 + 2], Wc[4 * k4 + 3]);
      d0 += a0.x * wv.x + a0.y * wv.y + a0.z * wv.z + a0.w * wv.w;
      d1 += a1.x * wv.x + a1.y * wv.y + a1.z * wv.z + a1.w * wv.w;
    }
    d0 += __shfl_xor(d0, 1, 64); d0 += __shfl_xor(d0, 2, 64);
    d0 += __shfl_xor(d0, 4, 64); d0 += __shfl_xor(d0, 8, 64);
    d1 += __shfl_xor(d1, 1, 64); d1 += __shfl_xor(d1, 2, 64);
    d1 += __shfl_xor(d1, 4, 64); d1 += __shfl_xor(d1, 8, 64);
    if (kp == 0) {
      gstore(dst0 + col, d0 + bqS[col]);
      gstore(dst1 + col, d1 + bqS[col]);
    }
  };
  auto projK_G2 = [&](const float* A0, const float* A1, float* dst0, float* dst1) {
    int col = lane >> 4, kp = lane & 15;
    const float* Wc = WKS + col * 260 + kp * 16;
    const float* Ak0 = A0 + kp * 16;
    const float* Ak1 = A1 + kp * 16;
    float v0[16], v1[16];
#pragma unroll
    for (int k2 = 0; k2 < 8; ++k2) {     // one merged burst: 16 gload2
      float2 a0 = gload2(Ak0 + 2 * k2);
      float2 a1 = gload2(Ak1 + 2 * k2);
      v0[2 * k2] = a0.x; v0[2 * k2 + 1] = a0.y;
      v1[2 * k2] = a1.x; v1[2 * k2 + 1] = a1.y;
    }
    float d0 = 0.f, d1 = 0.f;
#pragma unroll
    for (int e = 0; e < 16; ++e) { d0 += v0[e] * Wc[e]; d1 += v1[e] * Wc[e]; }
    d0 += __shfl_xor(d0, 1, 64); d0 += __shfl_xor(d0, 2, 64);
    d0 += __shfl_xor(d0, 4, 64); d0 += __shfl_xor(d0, 8, 64);
    d1 += __shfl_xor(d1, 1, 64); d1 += __shfl_xor(d1, 2, 64);
    d1 += __shfl_xor(d1, 4, 64); d1 += __shfl_xor(d1, 8, 64);
    if (kp == 0) {
      gstore(dst0 + col, d0 + bkS[col]);
      gstore(dst1 + col, d1 + bkS[col]);
    }
  };
  auto projK_L2 = [&](const uint* A0, const uint* A1, float* dst0, float* dst1) {
    int col = lane >> 4, kp = lane & 15;
    const float* Wc = WKS + col * 260 + kp * 16;
    float d0 = 0.f, d1 = 0.f;
#pragma unroll
    for (int q = 0; q < 2; ++q) {
      uint4 a0 = *(const uint4*)&A0[kp * 8 + q * 4];
      uint4 a1 = *(const uint4*)&A1[kp * 8 + q * 4];
      const float* wq = Wc + q * 8;
      float2 p0 = unpack2(a0.x), p1 = unpack2(a0.y), p2 = unpack2(a0.z), p3 = unpack2(a0.w);
      d0 += p0.x * wq[0] + p0.y * wq[1] + p1.x * wq[2] + p1.y * wq[3]
          + p2.x * wq[4] + p2.y * wq[5] + p3.x * wq[6] + p3.y * wq[7];
      float2 q0 = unpack2(a1.x), q1 = unpack2(a1.y), q2 = unpack2(a1.z), q3 = unpack2(a1.w);
      d1 += q0.x * wq[0] + q0.y * wq[1] + q1.x * wq[2] + q1.y * wq[3]
          + q2.x * wq[4] + q2.y * wq[5] + q3.x * wq[6] + q3.y * wq[7];
    }
    d0 += __shfl_xor(d0, 1, 64); d0 += __shfl_xor(d0, 2, 64);
    d0 += __shfl_xor(d0, 4, 64); d0 += __shfl_xor(d0, 8, 64);
    d1 += __shfl_xor(d1, 1, 64); d1 += __shfl_xor(d1, 2, 64);
    d1 += __shfl_xor(d1, 4, 64); d1 += __shfl_xor(d1, 8, 64);
    if (kp == 0) {
      gstore(dst0 + col, d0 + bkS[col]);
      gstore(dst1 + col, d1 + bkS[col]);
    }
  };

  // ---- t=0 init per pipe ----
  auto initPipe = [&](Pipe& P) {
    if (tid < 256) {
      int e = cg * 256 + tid;          // 16384 floats over 64 blocks
      gstore(P.MB0 + e, 0.f);
      int r = e >> 11, s = (e >> 8) & 7, hd = e & 255;
      gstore(mem_out + ((size_t)(P.row0 + r) * NS + s) * HDIM + hd,
             Xp[(size_t)(P.row0 + r) * HDIM + hd]);
    }
    if (cg == 0 && tid < 64) gstore(probs_out + P.row0 * NS + tid, 0.f);
    {
      int r = tid >> 6, c4 = (tid & 63) * 4;   // prestage hloc = Xp[t=1] (pack f16)
      const float* src = &Xp[((size_t)BATCH + P.row0 + r) * HDIM + c4];
      float4 a = *(const float4*)src;
      *(uint2*)&P.hloc[r * 132 + c4 / 2] = make_uint2(pack2(a.x, a.y), pack2(a.z, a.w));
    }
  };
  // S1a for t=1: q from Xp[1], k from Xp[0] broadcast to all slots
  auto s1aInit = [&](Pipe& P) {
    int col = lane >> 4, kp = lane & 15;
    {
      const float* Wc = WQS + col * 260 + kp * 16;
      const float* Ak = Xp + ((size_t)BATCH + P.row0 + w) * HDIM + kp * 16;
      float d = 0.f;
#pragma unroll
      for (int k4 = 0; k4 < 4; ++k4) {
        float4 a = *(const float4*)(Ak + 4 * k4);
        d += a.x * Wc[4 * k4] + a.y * Wc[4 * k4 + 1] + a.z * Wc[4 * k4 + 2] + a.w * Wc[4 * k4 + 3];
      }
      d += __shfl_xor(d, 1, 64); d += __shfl_xor(d, 2, 64);
      d += __shfl_xor(d, 4, 64); d += __shfl_xor(d, 8, 64);
      if (kp == 0) gstore(P.QPRE + w * HDIM + QC0 + col, d + bqS[col]);
    }
    {
      const float* Wc = WKS + col * 260 + kp * 16;
      const float* Ak = Xp + (size_t)(P.row0 + w) * HDIM + kp * 16;
      float d = 0.f;
#pragma unroll
      for (int k4 = 0; k4 < 4; ++k4) {
        float4 a = *(const float4*)(Ak + 4 * k4);
        d += a.x * Wc[4 * k4] + a.y * Wc[4 * k4 + 1] + a.z * Wc[4 * k4 + 2] + a.w * Wc[4 * k4 + 3];
      }
      d += __shfl_xor(d, 1, 64); d += __shfl_xor(d, 2, 64);
      d += __shfl_xor(d, 4, 64); d += __shfl_xor(d, 8, 64);
      if (kp == 0) {
        float vk = d + bkS[col];
#pragma unroll
        for (int s = 0; s < NS; ++s) gstore(P.KPRE + (w * 8 + s) * HDIM + QC0 + col, vk);
      }
    }
  };

  // ---- merged H section: load both pipes' data in one burst, then compute ----
  auto hSecM = [&](int ci, int t, float* memCur, float4 hv0, float4 hv1) {
    const int hd0 = lane * 4;
    const uint* z0r = P0.Z2u + w * 512;
    const uint* z1r = P1.Z2u + w * 512;
    // ---- one merged gather burst (f16x2) ----
    uint2 cu0 = gloadu2(z0r + 384 + lane * 2);
    uint2 cu1 = gloadu2(z1r + 384 + lane * 2);
    uint2 ga0 = gloadu2(z0r + 6 * lane), gb0 = gloadu2(z0r + 6 * lane + 2), gc0 = gloadu2(z0r + 6 * lane + 4);
    uint2 ga1 = gloadu2(z1r + 6 * lane), gb1 = gloadu2(z1r + 6 * lane + 2), gc1 = gloadu2(z1r + 6 * lane + 4);
    float4 ls4 = *(const float4*)&LNS_[hd0];
    float4 lb4 = *(const float4*)&LNB_[hd0];
    float lsv[4] = {ls4.x, ls4.y, ls4.z, ls4.w};
    float lbv[4] = {lb4.x, lb4.y, lb4.z, lb4.w};
#pragma unroll
    for (int p = 0; p < 2; ++p) {
      Pipe& P = p ? P1 : P0;
      float cc[4];
      {
        uint2 cu = p ? cu1 : cu0;
        float2 x = unpack2(cu.x), y = unpack2(cu.y);
        cc[0] = x.x; cc[1] = x.y; cc[2] = y.x; cc[3] = y.y;
      }
      float g[12];
      {
        uint2 a = p ? ga1 : ga0, b = p ? gb1 : gb0, c = p ? gc1 : gc0;
        float2 t0 = unpack2(a.x), t1 = unpack2(a.y), t2 = unpack2(b.x),
               t3 = unpack2(b.y), t4 = unpack2(c.x), t5 = unpack2(c.y);
        g[0] = t0.x; g[1] = t0.y; g[2] = t1.x; g[3] = t1.y;
        g[4] = t2.x; g[5] = t2.y; g[6] = t3.x; g[7] = t3.y;
        g[8] = t4.x; g[9] = t4.y; g[10] = t5.x; g[11] = t5.y;
      }
      float4 hv = p ? hv1 : hv0;
      float s1 = cc[0] + cc[1] + cc[2] + cc[3];
      float s2 = cc[0] * cc[0] + cc[1] * cc[1] + cc[2] * cc[2] + cc[3] * cc[3];
#pragma unroll
      for (int m = 1; m < 64; m <<= 1) { s1 += __shfl_xor(s1, m, 64); s2 += __shfl_xor(s2, m, 64); }
      float mean = s1 * (1.f / 256.f);
      float inv = rsqrtf(s2 * (1.f / 256.f) - mean * mean + 1e-5f);
      float viv[4];
      {
        uint2 vu = *(const uint2*)&P.hloc[w * 132 + lane * 2];
        float2 x = unpack2(vu.x), y = unpack2(vu.y);
        viv[0] = x.x; viv[1] = x.y; viv[2] = y.x; viv[3] = y.y;
      }
      float4 xp4 = *(const float4*)&Xp[((size_t)t * BATCH + P.row0 + w) * HDIM + hd0];
      float xpv[4] = {xp4.x, xp4.y, xp4.z, xp4.w};
      float hivv[4] = {hv.x, hv.y, hv.z, hv.w};
      float cp = P.cpS[w * 8 + ci];
      float hn[4];
#pragma unroll
      for (int j = 0; j < 4; ++j) {
        float z0 = g[3 * j], z1v = g[3 * j + 1], z2g = g[3 * j + 2];
        float gm = fmaxf(z0, fmaxf(z1v, z2g));
        float e0 = __expf(z0 - gm), e1 = __expf(z1v - gm), e2 = __expf(z2g - gm);
        float act = ftanh((cc[j] - mean) * inv * lsv[j] + lbv[j]);
        float hc = (e0 * xpv[j] * 0.f + e0 * viv[j] + e1 * hivv[j] + e2 * act) * __builtin_amdgcn_rcpf(e0 + e1 + e2);
        hn[j] = xpv[j] * (1.f - cp) + hc * cp;
      }
      *(uint2*)&P.hloc[w * 132 + lane * 2] =
          make_uint2(pack2(hn[0], hn[1]), pack2(hn[2], hn[3]));
      if (lane == cg) {
        float* mp = memCur + ((size_t)(P.row0 + w) * NS + ci) * HDIM + QC0;
        gstore2(mp, hn[0], hn[1]);
        gstore2(mp + 2, hn[2], hn[3]);
      }
    }
  };

  // ---- cell section 1: merged Z2(ci) for both pipes (f16 path) ----
  auto cellS1M = [&](int phRdy) {
    waitBoth(phRdy);
    // gather both pipes' z1 rows (f16x2): row r16, 4 uints per chunk at c4p
    const int r16 = tid >> 5, c4p = (tid & 31) * 4;
    const uint* zr = ((r16 < 8) ? P0.Z1u : P1.Z1u) + (r16 & 7) * 512 + c4p;
    uint2 pf[8];
#pragma unroll
    for (int ch = 0; ch < 4; ++ch) {
      pf[ch * 2] = gloadu2(zr + ch * 128);
      pf[ch * 2 + 1] = gloadu2(zr + ch * 128 + 2);
    }
    *(uint4*)&Az0[r16 * 132 + c4p] = make_uint4(pf[0].x, pf[0].y, pf[1].x, pf[1].y);
    __syncthreads();
    float za00 = 0.f, za01 = 0.f, za10 = 0.f, za11 = 0.f;
#pragma unroll
    for (int ch = 0; ch < 4; ++ch) {
      const uint* buf = (ch & 1) ? Az1 : Az0;
      uint* nbuf = (ch & 1) ? Az0 : Az1;
      const int kbp = w * 16, kw0 = ch * 128 + kbp;
#pragma unroll
      for (int kk = 0; kk < 16; kk += 4) {
        uint4 x = *(const uint4*)&buf[rl * 132 + kbp + kk];
        uint4 y = *(const uint4*)&buf[(rl + 8) * 132 + kbp + kk];
        uint4 u0 = *(const uint4*)&W2b[cl * 516 + kw0 + kk];
        uint4 u1 = *(const uint4*)&W2b[(cl + 8) * 516 + kw0 + kk];
        za00 = dot8(za00, x, u0); za01 = dot8(za01, x, u1);
        za10 = dot8(za10, y, u0); za11 = dot8(za11, y, u1);
      }
      if (ch < 3) {
        int b2i = (ch + 1) * 2;
        *(uint4*)&nbuf[r16 * 132 + c4p] =
            make_uint4(pf[b2i].x, pf[b2i].y, pf[b2i + 1].x, pf[b2i + 1].y);
      }
      __syncthreads();
    }
    redFinishM(za00, za01, za10, za11, P0.Z2u, P1.Z2u, b2s, false);
  };

  // ---- cell section 2: window + H(ci) + merged Z1(ci+1) ----
  auto cellS2M = [&](int ci, int t, int phA, float* memCur) {
    const bool lastT = (t == T_LEN - 1);
    // hiv (Ast slot ci, row w) for both pipes before restage
    float4 hv0, hv1;
    {
      uint2 u0 = *(const uint2*)&Ast0[w * 132 + lane * 2];
      uint2 u1 = *(const uint2*)&Ast1[w * 132 + lane * 2];
      float2 a = unpack2(u0.x), b = unpack2(u0.y), c = unpack2(u1.x), d = unpack2(u1.y);
      hv0 = make_float4(a.x, a.y, b.x, b.y);
      hv1 = make_float4(c.x, c.y, d.x, d.y);
    }
    __syncthreads();
    if (ci < 7) {
      // restage both Ast = MbNew slot ci+1 (fully blended in P1), pack f16
      float* MbN0 = (t & 1) ? P0.MB1 : P0.MB0;
      float* MbN1 = (t & 1) ? P1.MB1 : P1.MB0;
      const int r16 = tid >> 5, c8 = (tid & 31) * 8, rr = r16 & 7;
      float* mb = (r16 < 8) ? MbN0 : MbN1;
      uint* as = (r16 < 8) ? Ast0 : Ast1;
      const float* src = mb + (rr * NS + ci + 1) * HDIM + c8;
      float2 a0 = gload2(src), a1 = gload2(src + 2), a2 = gload2(src + 4), a3 = gload2(src + 6);
      *(uint4*)&as[rr * 132 + c8 / 2] = make_uint4(
          pack2(a0.x, a0.y), pack2(a1.x, a1.y), pack2(a2.x, a2.y), pack2(a3.x, a3.y));
    } else if (!lastT) {
      // KPRE(s=6) from memCur slot 6 (visible: waited sigB(6) in cellS1(7))
      projK_G2(memCur + ((size_t)(P0.row0 + w) * NS + 6) * HDIM,
               memCur + ((size_t)(P1.row0 + w) * NS + 6) * HDIM,
               P0.KPRE + (w * 8 + 6) * HDIM + QC0,
               P1.KPRE + (w * 8 + 6) * HDIM + QC0);
    }
    __syncthreads();
    float b00 = 0.f, b01 = 0.f, b10 = 0.f, b11 = 0.f;
    if (ci < 7) z1HalfM(Ast0, Ast1, 128, b00, b01, b10, b11);   // Mn-half of Z1(ci+1)
    waitBoth(phA);
    hSecM(ci, t, memCur, hv0, hv1);
    __syncthreads();
    if (ci < 7) {
      z1HalfM(hloc0, hloc1, 0, b00, b01, b10, b11);   // h-half of Z1(ci+1)
      redFinishM(b00, b01, b10, b11, P0.Z1u, P1.Z1u, b1s, true);
    } else if (!lastT) {
      // KPRE(s=7) from new h (LDS f16) — pre-sigB
      projK_L2(&hloc0[w * 132], &hloc1[w * 132],
               P0.KPRE + (w * 8 + 7) * HDIM + QC0,
               P1.KPRE + (w * 8 + 7) * HDIM + QC0);
    }
  };

  // ---- B-window: S1a(t+1) pieces merged, drained by NEXT signal ----
  auto bWinM = [&](int ci, int t, float* memCur) {
    if (ci == 0) {
      projQ2(Xp + ((size_t)(t + 1) * BATCH + P0.row0 + w) * HDIM,
             Xp + ((size_t)(t + 1) * BATCH + P1.row0 + w) * HDIM,
             P0.QPRE + w * HDIM + QC0, P1.QPRE + w * HDIM + QC0);
    } else if (ci <= 6) {
      const int s = ci - 1;   // memCur slot s visible (waited sigB(s) in cellS1(ci))
      projK_G2(memCur + ((size_t)(P0.row0 + w) * NS + s) * HDIM,
               memCur + ((size_t)(P1.row0 + w) * NS + s) * HDIM,
               P0.KPRE + (w * 8 + s) * HDIM + QC0,
               P1.KPRE + (w * 8 + s) * HDIM + QC0);
    } else {
      // prestage hloc = Xp[t+1] for both pipes (merged 16-row pass, pack f16)
      const int r16 = tid >> 5, c8 = (tid & 31) * 8, rr = r16 & 7;
      Pipe& P = (r16 < 8) ? P0 : P1;
      const float* src = &Xp[((size_t)(t + 1) * BATCH + P.row0 + rr) * HDIM + c8];
      float4 a = *(const float4*)src;
      float4 b = *(const float4*)(src + 4);
      *(uint4*)&P.hloc[rr * 132 + c8 / 2] = make_uint4(
          pack2(a.x, a.y), pack2(a.z, a.w), pack2(b.x, b.y), pack2(b.z, b.w));
    }
  };

  // ================= init + time loop =================
  __syncthreads();
  initPipe(P0); initPipe(P1);
  __syncthreads();
  s1aInit(P0); s1aInit(P1);
  int ph = 1;
  sigBoth(ph);
  waitBoth(ph);

  for (int t = 1; t < T_LEN; ++t) {
    const bool lastT = (t == T_LEN - 1);
    float* MbOld0 = ((t - 1) & 1) ? P0.MB1 : P0.MB0;
    float* MbOld1 = ((t - 1) & 1) ? P1.MB1 : P1.MB0;
    const float* memPrev = mem_out + (size_t)(t - 1) * BATCH * NS * HDIM;
    float* memCur = mem_out + (size_t)t * BATCH * NS * HDIM;
    const float* probsPrev = probs_out + (size_t)(t - 1) * BATCH * NS;
    float* probsCur = probs_out + (size_t)t * BATCH * NS;

    // ---------- P1 (merged pipes) ----------
    // (1) q-LN merged — pre-wait (QPRE(t) visible transitively); qln packed f16 -> Az0
    {
      const int r16 = tid >> 5, hd0 = (tid & 31) * 8, row = r16 & 7;
      Pipe& P = (r16 < 8) ? P0 : P1;
      float q[8]; float s1 = 0.f, s2 = 0.f;
#pragma unroll
      for (int j = 0; j < 4; ++j) {
        float2 v = gload2(P.QPRE + row * HDIM + hd0 + 2 * j);
        q[2 * j] = v.x; q[2 * j + 1] = v.y;
        s1 += v.x + v.y; s2 += v.x * v.x + v.y * v.y;
      }
#pragma unroll
      for (int m = 1; m < 32; m <<= 1) { s1 += __shfl_xor(s1, m, 64); s2 += __shfl_xor(s2, m, 64); }
      float mean = s1 * (1.f / 256.f);
      float inv = rsqrtf(s2 * (1.f / 256.f) - mean * mean + 1e-5f);
      float qn[8];
#pragma unroll
      for (int j = 0; j < 8; ++j)
        qn[j] = (q[j] - mean) * inv * lnqs[hd0 + j] + lnqb[hd0 + j];
      *(uint4*)&Az0[r16 * 132 + hd0 / 2] = make_uint4(
          pack2(qn[0], qn[1]), pack2(qn[2], qn[3]), pack2(qn[4], qn[5]), pack2(qn[6], qn[7]));
    }
    // wait for all blocks' B(7) of t-1 (KPRE fresh) — hidden under q-LN above
    waitBoth(ph);
    {
      // (2) k-LN + beta merged: 128 krows x 4 threads (one 64-float burst)
      const int kr128 = tid >> 2, u4 = tid & 3;
      Pipe& P = (kr128 < 64) ? P0 : P1;
      const int kr = kr128 & 63;
      const int rr16 = (kr >> 3) + ((kr128 < 64) ? 0 : 8);
      const float* kp = P.KPRE + kr * HDIM + u4 * 64;
      float kv[64]; float s1 = 0.f, s2 = 0.f;
#pragma unroll
      for (int e = 0; e < 32; ++e) {
        float2 v = gload2(kp + 2 * e);
        kv[2 * e] = v.x; kv[2 * e + 1] = v.y;
        s1 += v.x + v.y; s2 += v.x * v.x + v.y * v.y;
      }
      s1 += __shfl_xor(s1, 1, 64); s1 += __shfl_xor(s1, 2, 64);
      s2 += __shfl_xor(s2, 1, 64); s2 += __shfl_xor(s2, 2, 64);
      float mean = s1 * (1.f / 256.f);
      float inv = rsqrtf(s2 * (1.f / 256.f) - mean * mean + 1e-5f);
      float dot = 0.f;
#pragma unroll
      for (int e = 0; e < 64; e += 2) {
        int hd = u4 * 64 + e;
        float2 q2 = unpack2(Az0[rr16 * 132 + hd / 2]);
        float kl0 = (kv[e] - mean) * inv * LNKS_[hd] + LNKB_[hd];
        float kl1 = (kv[e + 1] - mean) * inv * LNKS_[hd + 1] + LNKB_[hd + 1];
        dot += fmaxf(q2.x + kl0, 0.f) * Wbs[hd];
        dot += fmaxf(q2.y + kl1, 0.f) * Wbs[hd + 1];
      }
      dot += __shfl_xor(dot, 1, 64); dot += __shfl_xor(dot, 2, 64);
      if (u4 == 0) P.betaS[kr] = (dot + bbetaS[0]) * 0.0625f;
    }
    __syncthreads();
    // (3) softmax + mask + p/cp/rcp (16 threads: 2 pipes x 8 rows)
    if (tid < 16) {
      Pipe& P = (tid < 8) ? P0 : P1;
      int r = tid & 7, b = P.row0 + r;
      float pp[8], pcp[8], run = 0.f;
#pragma unroll
      for (int s = 0; s < 8; s += 2) {
        float2 v = gload2(probsPrev + b * NS + s);
        pp[s] = v.x; pp[s + 1] = v.y;
      }
#pragma unroll
      for (int s = 0; s < 8; ++s) { run += pp[s]; pcp[s] = run; }
      float bmax = P.betaS[r * 8];
#pragma unroll
      for (int s = 1; s < 8; ++s) bmax = fmaxf(bmax, P.betaS[r * 8 + s]);
      float xm[8], ssum = 0.f;
#pragma unroll
      for (int s = 0; s < 8; ++s) {
        float mi = (s < 7) ? ((pcp[s + 1] < 1e-5f) ? 0.f : pcp[s + 1]) : 1.f;
        xm[s] = __expf(P.betaS[r * 8 + s] - bmax) * mi;
        ssum += fabsf(xm[s]);
      }
      float denom = fmaxf(ssum, 1e-12f);
      float run2 = 0.f, pn[8];
#pragma unroll
      for (int s = 0; s < 8; ++s) {
        pn[s] = xm[s] / denom; run2 += pn[s];
        P.cpS[r * 8 + s] = run2;
      }
      if (cg == tid) {   // 16 distinct writer blocks
#pragma unroll
        for (int s = 0; s < 8; s += 2) gstore2(probsCur + b * NS + s, pn[s], pn[s + 1]);
      }
      float run3 = 0.f;
#pragma unroll
      for (int s = 7; s >= 0; --s) { run3 += pn[s]; P.rcpS[r * 8 + s] = run3; }
    }
    __syncthreads();
    // (4) M-state owner update merged (2 pipes x 8r x 8s x 4c = 512 threads)
    {
      Pipe& P = (tid < 256) ? P0 : P1;
      float* MbOld = (tid < 256) ? MbOld0 : MbOld1;
      float* MbNew = (t & 1) ? P.MB1 : P.MB0;
      int e = tid & 255;
      int r = e >> 5, s = (e >> 2) & 7, c = e & 3;
      int idx = (r * NS + s) * HDIM + QC0 + c;
      float rc = P.rcpS[r * 8 + s];
      float mo = gload(MbOld + idx);
      float cm = gload(memPrev + ((size_t)(P.row0 + r) * NS + s) * HDIM + QC0 + c);
      gstore(MbNew + idx, mo * (1.f - rc) + cm * rc);
    }
    // (5) stage Ast = blend(MbOld, memPrev) slot0 merged, pack f16
    {
      const int r16 = tid >> 5, c8 = (tid & 31) * 8, rr = r16 & 7;
      Pipe& P = (r16 < 8) ? P0 : P1;
      float* MbOld = (r16 < 8) ? MbOld0 : MbOld1;
      float rc0 = P.rcpS[rr * 8];
      const float* mo = MbOld + (rr * NS) * HDIM + c8;
      const float* cm = memPrev + ((size_t)(P.row0 + rr) * NS) * HDIM + c8;
      float2 m0 = gload2(mo), m1 = gload2(mo + 2), m2 = gload2(mo + 4), m3 = gload2(mo + 6);
      float2 c0 = gload2(cm), c1 = gload2(cm + 2), c2 = gload2(cm + 4), c3 = gload2(cm + 6);
      uint* as = (r16 < 8) ? Ast0 : Ast1;
      *(uint4*)&as[rr * 132 + c8 / 2] = make_uint4(
          pack2(m0.x * (1.f - rc0) + c0.x * rc0, m0.y * (1.f - rc0) + c0.y * rc0),
          pack2(m1.x * (1.f - rc0) + c1.x * rc0, m1.y * (1.f - rc0) + c1.y * rc0),
          pack2(m2.x * (1.f - rc0) + c2.x * rc0, m2.y * (1.f - rc0) + c2.y * rc0),
          pack2(m3.x * (1.f - rc0) + c3.x * rc0, m3.y * (1.f - rc0) + c3.y * rc0));
    }
    __syncthreads();
    {
      // merged Z1(0): Mn-half (Ast) + h-half (hloc)
      float a00 = 0.f, a01 = 0.f, a10 = 0.f, a11 = 0.f;
      z1HalfM(Ast0, Ast1, 128, a00, a01, a10, a11);
      z1HalfM(hloc0, hloc1, 0, a00, a01, a10, a11);
      redFinishM(a00, a01, a10, a11, P0.Z1u, P1.Z1u, b1s, true);
    }
    ++ph; sigBoth(ph);

    // ---------- cells ----------
    for (int ci = 0; ci < NS; ++ci) {
      const int phRdy = ph;
      cellS1M(phRdy);
      ++ph; sigBoth(ph);
      cellS2M(ci, t, ph, memCur);
      ++ph; sigBoth(ph);
      if (!lastT) bWinM(ci, t, memCur);
    }
    // no end-of-loop wait — next P1's q-LN runs pre-wait; waitBoth(ph) after q-LN
  }
}

extern "C" void kernel_launch(void* const* d_in, const int* in_sizes, int n_in,
                              void* d_out, int out_size, void* d_ws, size_t ws_size,
                              hipStream_t stream) {
  (void)in_sizes; (void)n_in; (void)out_size; (void)ws_size;
  const float* X     = (const float*)d_in[0];
  const float* Wp    = (const float*)d_in[3];
  const float* bp    = (const float*)d_in[4];
  const float* lns   = (const float*)d_in[5];
  const float* lnb   = (const float*)d_in[6];
  const float* Wq    = (const float*)d_in[7];
  const float* bq    = (const float*)d_in[8];
  const float* lnqs  = (const float*)d_in[9];
  const float* lnqb  = (const float*)d_in[10];
  const float* Wk    = (const float*)d_in[11];
  const float* bk    = (const float*)d_in[12];
  const float* lnks  = (const float*)d_in[13];
  const float* lnkb  = (const float*)d_in[14];
  const float* Wbeta = (const float*)d_in[15];
  const float* bbeta = (const float*)d_in[16];
  const float* W1    = (const float*)d_in[17];
  const float* b1    = (const float*)d_in[18];
  const float* W2    = (const float*)d_in[19];
  const float* b2    = (const float*)d_in[20];

  float* out       = (float*)d_out;
  float* out_xp    = out;
  float* out_mem   = out + (size_t)T_LEN * BATCH * HDIM;
  float* out_probs = out_mem + (size_t)T_LEN * BATCH * NS * HDIM;
  float* ws        = (float*)d_ws;

  hipLaunchKernelGGL(init_ctrl, dim3(4), dim3(256), 0, stream, (int*)d_ws);
  hipLaunchKernelGGL(xp_kernel, dim3(1024), dim3(256), 0, stream, X, Wp, bp, lns, lnb, out_xp);
  hipLaunchKernelGGL(omr_main, dim3(256), dim3(NTHR), 0, stream,
                     out_xp, Wq, bq, lnqs, lnqb, Wk, bk, lnks, lnkb, Wbeta, bbeta,
                     W1, b1, W2, b2, lns, lnb, out_mem, out_probs, ws);
}

// Round 9
// 12452.730 us; speedup vs baseline: 1.6640x; 1.0631x over previous
//
#include <hip/hip_runtime.h>
#include <hip/hip_bf16.h>
#include <math.h>

#define T_LEN 128
#define BATCH 64
#define IND   512
#define HDIM  256
#define NS    8
#define H4    1024
#define NTHR  512
#define RPC   8        // rows per cluster (pipeline)
#define CSTRIDE 67584  // floats per cluster in ws

typedef unsigned long long ull;
typedef unsigned int uint;
typedef unsigned short ushort;
typedef _Float16 f16x2 __attribute__((ext_vector_type(2)));
typedef _Float16 half8 __attribute__((ext_vector_type(8)));
typedef float f32x4 __attribute__((ext_vector_type(4)));

// ---- LLC-coherent accessors (bypass per-XCD L2): agent-scope relaxed atomics ----
__device__ __forceinline__ float gload(const float* p) {
  return __hip_atomic_load(p, __ATOMIC_RELAXED, __HIP_MEMORY_SCOPE_AGENT);
}
__device__ __forceinline__ float2 gload2(const float* p) {
  ull v = __hip_atomic_load((const ull*)p, __ATOMIC_RELAXED, __HIP_MEMORY_SCOPE_AGENT);
  return __builtin_bit_cast(float2, v);
}
__device__ __forceinline__ void gstore(float* p, float v) {
  __hip_atomic_store(p, v, __ATOMIC_RELAXED, __HIP_MEMORY_SCOPE_AGENT);
}
__device__ __forceinline__ void gstore2(float* p, float a, float b) {
  float2 t = make_float2(a, b);
  __hip_atomic_store((ull*)p, __builtin_bit_cast(ull, t), __ATOMIC_RELAXED, __HIP_MEMORY_SCOPE_AGENT);
}
__device__ __forceinline__ void gstoreu2(uint* p, uint a, uint b) {
  uint2 t = make_uint2(a, b);
  __hip_atomic_store((ull*)p, __builtin_bit_cast(ull, t), __ATOMIC_RELAXED, __HIP_MEMORY_SCOPE_AGENT);
}
__device__ __forceinline__ ull gloadU(const uint* p) {
  return __hip_atomic_load((const ull*)p, __ATOMIC_RELAXED, __HIP_MEMORY_SCOPE_AGENT);
}
__device__ __forceinline__ uint2 gloadu2(const uint* p) {
  ull v = __hip_atomic_load((const ull*)p, __ATOMIC_RELAXED, __HIP_MEMORY_SCOPE_AGENT);
  return __builtin_bit_cast(uint2, v);
}

// ---- f16 pack/unpack ----
__device__ __forceinline__ uint pack2(float a, float b) {
  f16x2 v; v.x = (_Float16)a; v.y = (_Float16)b;
  return __builtin_bit_cast(uint, v);
}
__device__ __forceinline__ float2 unpack2(uint u) {
  f16x2 v = __builtin_bit_cast(f16x2, u);
  return make_float2((float)v.x, (float)v.y);
}
__device__ __forceinline__ half8 mk8(ull lo, ull hi) {
  struct U { ull a, b; } u{lo, hi};
  return __builtin_bit_cast(half8, u);
}
__device__ __forceinline__ half8 bc8(uint4 v) {
  return __builtin_bit_cast(half8, v);
}

// fast tanh via hw exp
__device__ __forceinline__ float ftanh(float x) {
  float xc = fminf(fmaxf(x, -9.f), 9.f);
  float t = __expf(2.f * xc);
  return (t - 1.f) * __builtin_amdgcn_rcpf(t + 1.f);
}

extern "C" __global__ void init_ctrl(int* ctrl) {
  int t = blockIdx.x * blockDim.x + threadIdx.x;
  if (t < 1024) ctrl[t] = 0;
}

// ---------------- Xp = tanh(LN(X @ W_proj + b)) ----------------
extern "C" __global__ __launch_bounds__(256) void xp_kernel(
    const float* __restrict__ X, const float* __restrict__ Wp, const float* __restrict__ bp,
    const float* __restrict__ lns, const float* __restrict__ lnb, float* __restrict__ out_xp)
{
  __shared__ float Xs[8 * IND];
  __shared__ float Ys[8 * HDIM];
  const int tid = threadIdx.x;
  const size_t base = (size_t)blockIdx.x * 8;
  const float* Xb = X + base * IND;
  for (int e = tid; e < 8 * IND / 4; e += 256) ((float4*)Xs)[e] = ((const float4*)Xb)[e];
  __syncthreads();
  float acc[8];
#pragma unroll
  for (int r = 0; r < 8; ++r) acc[r] = 0.f;
  for (int k = 0; k < IND; ++k) {
    float wv = Wp[k * HDIM + tid];
#pragma unroll
    for (int r = 0; r < 8; ++r) acc[r] += Xs[r * IND + k] * wv;
  }
  float bpv = bp[tid];
#pragma unroll
  for (int r = 0; r < 8; ++r) Ys[r * HDIM + tid] = acc[r] + bpv;
  __syncthreads();
  int w = tid >> 6, lane = tid & 63;
  for (int rr = 0; rr < 2; ++rr) {
    int r = w * 2 + rr;
    float v[4]; float s1 = 0.f, s2 = 0.f;
#pragma unroll
    for (int e = 0; e < 4; ++e) { v[e] = Ys[r * HDIM + lane + 64 * e]; s1 += v[e]; s2 += v[e] * v[e]; }
#pragma unroll
    for (int off = 32; off > 0; off >>= 1) { s1 += __shfl_xor(s1, off, 64); s2 += __shfl_xor(s2, off, 64); }
    float m = s1 / 256.f;
    float iv = rsqrtf(s2 / 256.f - m * m + 1e-5f);
#pragma unroll
    for (int e = 0; e < 4; ++e) {
      int hd = lane + 64 * e;
      out_xp[(base + r) * HDIM + hd] = tanhf((v[e] - m) * iv * lns[hd] + lnb[hd]);
    }
  }
}

// ws float layout: [0..1023] int flags (cluster cl: ints [cl*64, cl*64+64)), 8 clusters;
// data base = 1024; per cluster cl (8 clusters of 8 rows), stride 67584:
//   QPRE +0 (2048), KPRE +2048 (16384), MB0 +18432 (16384), MB1 +34816 (16384),
//   Z1c +51200 (f16x2: 8*512 uints), Z2c +59392 (f16x2: 8*512 uints)

struct Pipe {
  float *QPRE, *KPRE, *MB0, *MB1;
  uint *Z1u, *Z2u;
  int* flags;
  uint *hloc, *Ast;
  float *cpS, *rcpS, *betaS;
  int row0;
};

// ---------------- main recurrent kernel: 8 clusters, 2 pipelines per block ----------------
extern "C" __global__ __launch_bounds__(NTHR, 1) void omr_main(
    const float* __restrict__ Xp,
    const float* __restrict__ Wq, const float* __restrict__ bq,
    const float* __restrict__ lnqs, const float* __restrict__ lnqb,
    const float* __restrict__ Wk, const float* __restrict__ bk,
    const float* __restrict__ lnks, const float* __restrict__ lnkb,
    const float* __restrict__ Wbeta, const float* __restrict__ bbeta,
    const float* __restrict__ W1, const float* __restrict__ b1,
    const float* __restrict__ W2, const float* __restrict__ b2,
    const float* __restrict__ lns, const float* __restrict__ lnb,
    float* __restrict__ mem_out, float* __restrict__ probs_out, float* __restrict__ ws)
{
  const int tid = threadIdx.x;
  const int sc = blockIdx.x >> 6;   // supercluster (4), pipes = clusters 2sc, 2sc+1
  const int cg = blockIdx.x & 63;   // column group within supercluster
  const int ZC0 = cg * 16;          // z1/z2 cols owned
  const int QC0 = cg * 4;           // q/k/h cols owned
  const int w = tid >> 6, lane = tid & 63;

  // LDS ~90 KB
  __shared__ uint W1b[16 * 260];     // f16x2 W1 col slice [col][kpair]
  __shared__ uint W2b[16 * 516];     // f16x2 W2 col slice [col][kpair]
  __shared__ uint hloc0[RPC * 132], hloc1[RPC * 132];  // f16x2 rows
  __shared__ uint Ast0[RPC * 132], Ast1[RPC * 132];
  __shared__ uint Az0[16 * 132];                        // q-LN staging (f16x2)
  __shared__ float redS[8 * 260];                       // split-K partials (16x16)
  __shared__ float LNS_[256], LNB_[256], LNKS_[256], LNKB_[256], Wbs[256];
  __shared__ float WQS[4 * 260], WKS[4 * 260];
  __shared__ float cp0[64], cp1[64], rcp0[64], rcp1[64], bet0[64], bet1[64];
  __shared__ float b1s[16], b2s[16], bqS[4], bkS[4], bbetaS[1];

  auto mkPipe = [&](int p, uint* hl, uint* as, float* cp, float* rcp, float* bet) {
    Pipe P;
    int clid = sc * 2 + p;
    float* base = ws + 1024 + (size_t)clid * CSTRIDE;
    P.QPRE = base; P.KPRE = base + 2048;
    P.MB0 = base + 18432; P.MB1 = base + 34816;
    P.Z1u = (uint*)(base + 51200); P.Z2u = (uint*)(base + 59392);
    P.flags = (int*)ws + clid * 64;
    P.hloc = hl; P.Ast = as; P.cpS = cp; P.rcpS = rcp; P.betaS = bet;
    P.row0 = clid * RPC;
    return P;
  };
  Pipe P0 = mkPipe(0, hloc0, Ast0, cp0, rcp0, bet0);
  Pipe P1 = mkPipe(1, hloc1, Ast1, cp1, rcp1, bet1);

  // ---- resident weights / params (f16 pairs along K) ----
  for (int e = tid; e < 16 * 256; e += NTHR) {
    int kp = e >> 4, c = e & 15;
    W1b[c * 260 + kp] = pack2(W1[(size_t)(2 * kp) * H4 + ZC0 + c],
                              W1[(size_t)(2 * kp + 1) * H4 + ZC0 + c]);
  }
  for (int e = tid; e < 16 * 512; e += NTHR) {
    int kp = e >> 4, c = e & 15;
    W2b[c * 516 + kp] = pack2(W2[(size_t)(2 * kp) * H4 + ZC0 + c],
                              W2[(size_t)(2 * kp + 1) * H4 + ZC0 + c]);
  }
  for (int e = tid; e < 2048; e += NTHR) {
    int s = e >> 10, c = (e >> 8) & 3, k = e & 255;
    (s ? WKS : WQS)[c * 260 + k] = (s ? Wk : Wq)[k * HDIM + QC0 + c];
  }
  if (tid < 256) {
    LNS_[tid] = lns[tid];  LNB_[tid] = lnb[tid];
    LNKS_[tid] = lnks[tid]; LNKB_[tid] = lnkb[tid];
    Wbs[tid] = Wbeta[tid];
  }
  if (tid < 16) { b1s[tid] = b1[ZC0 + tid]; b2s[tid] = b2[ZC0 + tid]; }
  if (tid < 4)  { bqS[tid] = bq[QC0 + tid]; bkS[tid] = bk[QC0 + tid]; }
  if (tid == 0) bbetaS[0] = bbeta[0];

  // ---- barrier primitives ----
  auto waitBoth = [&](int p) {
    if (tid < 64) {
      while (__hip_atomic_load(P0.flags + tid, __ATOMIC_RELAXED, __HIP_MEMORY_SCOPE_AGENT) < p) {}
    } else if (tid < 128) {
      while (__hip_atomic_load(P1.flags + (tid - 64), __ATOMIC_RELAXED, __HIP_MEMORY_SCOPE_AGENT) < p) {}
    }
    __syncthreads();
  };
  auto sigBoth = [&](int p) {
    asm volatile("s_waitcnt vmcnt(0)" ::: "memory");
    __syncthreads();
    if (tid == 0) __hip_atomic_store(P0.flags + cg, p, __ATOMIC_RELAXED, __HIP_MEMORY_SCOPE_AGENT);
    if (tid == 1) __hip_atomic_store(P1.flags + cg, p, __ATOMIC_RELAXED, __HIP_MEMORY_SCOPE_AGENT);
  };

  // ==== MFMA GEMM helpers ====
  // Fragment mapping (v_mfma_f32_16x16x32_f16):
  //   A: row = lane&15, k = (lane>>4)*8 + j  (8 f16 = 4 uints, contiguous kpairs)
  //   B: col = lane&15, k = (lane>>4)*8 + j  (our W tiles are [col][kpair] -> contiguous)
  //   D: col = lane&15, row = (lane>>4)*4 + q
  // Wave w covers k-floats [w*32, w*32+32) of the 256-float half (Z1) / chunk (Z2).

  // Z1 half: A rows 0-7 from A0 (pipe0), 8-15 from A1 (pipe1); kwBaseP in kpair units.
  auto z1Mfma = [&](const uint* A0, const uint* A1, int kwBaseP, f32x4& acc) {
    const int row16 = lane & 15, kg = lane >> 4;
    const uint* ap = (row16 < 8) ? (A0 + row16 * 132) : (A1 + (row16 - 8) * 132);
    uint4 av = *(const uint4*)(ap + w * 16 + kg * 4);
    uint4 bv = *(const uint4*)&W1b[(lane & 15) * 260 + kwBaseP + w * 16 + kg * 4];
    acc = __builtin_amdgcn_mfma_f32_16x16x32_f16(bc8(av), bc8(bv), acc, 0, 0, 0);
  };

  // reduce split-K partials over 8 waves; pack f16x2 and store to dst rows (512 uints)
  auto redFinishMF = [&](f32x4 acc, uint* dst0, uint* dst1, const float* bias, bool doRelu) {
    __syncthreads();                    // protect prior redS readers
    const int col = lane & 15, rbase = (lane >> 4) * 4;
#pragma unroll
    for (int q = 0; q < 4; ++q)
      redS[w * 260 + (rbase + q) * 16 + col] = acc[q];
    __syncthreads();
    if (tid < 64) {
      int r = tid >> 2, c0 = (tid & 3) * 4;
      float v[4] = {0.f, 0.f, 0.f, 0.f};
#pragma unroll
      for (int w2 = 0; w2 < 8; ++w2) {
#pragma unroll
        for (int q = 0; q < 4; ++q) v[q] += redS[w2 * 260 + r * 16 + c0 + q];
      }
#pragma unroll
      for (int q = 0; q < 4; ++q) {
        v[q] += bias[c0 + q];
        if (doRelu) v[q] = fmaxf(v[q], 0.f);
      }
      uint* dst = (r < 8) ? dst0 : dst1;
      gstoreu2(dst + (r & 7) * 512 + (ZC0 + c0) / 2, pack2(v[0], v[1]), pack2(v[2], v[3]));
    }
  };

  // ---- merged 4-col projections for both pipes (wave w = row w) ----
  auto projQ2 = [&](const float* A0, const float* A1, float* dst0, float* dst1) {
    int col = lane >> 4, kp = lane & 15;
    const float* Wc = WQS + col * 260 + kp * 16;
    const float* Ak0 = A0 + kp * 16;
    const float* Ak1 = A1 + kp * 16;
    float d0 = 0.f, d1 = 0.f;
#pragma unroll
    for (int k4 = 0; k4 < 4; ++k4) {
      float4 a0 = *(const float4*)(Ak0 + 4 * k4);
      float4 a1 = *(const float4*)(Ak1 + 4 * k4);
      float4 wv = make_float4(Wc[4 * k4], Wc[4 * k4 + 1], Wc[4 * k4 + 2], Wc[4 * k4 + 3]);
      d0 += a0.x * wv.x + a0.y * wv.y + a0.z * wv.z + a0.w * wv.w;
      d1 += a1.x * wv.x + a1.y * wv.y + a1.z * wv.z + a1.w * wv.w;
    }
    d0 += __shfl_xor(d0, 1, 64); d0 += __shfl_xor(d0, 2, 64);
    d0 += __shfl_xor(d0, 4, 64); d0 += __shfl_xor(d0, 8, 64);
    d1 += __shfl_xor(d1, 1, 64); d1 += __shfl_xor(d1, 2, 64);
    d1 += __shfl_xor(d1, 4, 64); d1 += __shfl_xor(d1, 8, 64);
    if (kp == 0) {
      gstore(dst0 + col, d0 + bqS[col]);
      gstore(dst1 + col, d1 + bqS[col]);
    }
  };
  auto projK_G2 = [&](const float* A0, const float* A1, float* dst0, float* dst1) {
    int col = lane >> 4, kp = lane & 15;
    const float* Wc = WKS + col * 260 + kp * 16;
    const float* Ak0 = A0 + kp * 16;
    const float* Ak1 = A1 + kp * 16;
    float v0[16], v1[16];
#pragma unroll
    for (int k2 = 0; k2 < 8; ++k2) {     // one merged burst: 16 gload2
      float2 a0 = gload2(Ak0 + 2 * k2);
      float2 a1 = gload2(Ak1 + 2 * k2);
      v0[2 * k2] = a0.x; v0[2 * k2 + 1] = a0.y;
      v1[2 * k2] = a1.x; v1[2 * k2 + 1] = a1.y;
    }
    float d0 = 0.f, d1 = 0.f;
#pragma unroll
    for (int e = 0; e < 16; ++e) { d0 += v0[e] * Wc[e]; d1 += v1[e] * Wc[e]; }
    d0 += __shfl_xor(d0, 1, 64); d0 += __shfl_xor(d0, 2, 64);
    d0 += __shfl_xor(d0, 4, 64); d0 += __shfl_xor(d0, 8, 64);
    d1 += __shfl_xor(d1, 1, 64); d1 += __shfl_xor(d1, 2, 64);
    d1 += __shfl_xor(d1, 4, 64); d1 += __shfl_xor(d1, 8, 64);
    if (kp == 0) {
      gstore(dst0 + col, d0 + bkS[col]);
      gstore(dst1 + col, d1 + bkS[col]);
    }
  };
  auto projK_L2 = [&](const uint* A0, const uint* A1, float* dst0, float* dst1) {
    int col = lane >> 4, kp = lane & 15;
    const float* Wc = WKS + col * 260 + kp * 16;
    float d0 = 0.f, d1 = 0.f;
#pragma unroll
    for (int q = 0; q < 2; ++q) {
      uint4 a0 = *(const uint4*)&A0[kp * 8 + q * 4];
      uint4 a1 = *(const uint4*)&A1[kp * 8 + q * 4];
      const float* wq = Wc + q * 8;
      float2 p0 = unpack2(a0.x), p1 = unpack2(a0.y), p2 = unpack2(a0.z), p3 = unpack2(a0.w);
      d0 += p0.x * wq[0] + p0.y * wq[1] + p1.x * wq[2] + p1.y * wq[3]
          + p2.x * wq[4] + p2.y * wq[5] + p3.x * wq[6] + p3.y * wq[7];
      float2 q0 = unpack2(a1.x), q1 = unpack2(a1.y), q2 = unpack2(a1.z), q3 = unpack2(a1.w);
      d1 += q0.x * wq[0] + q0.y * wq[1] + q1.x * wq[2] + q1.y * wq[3]
          + q2.x * wq[4] + q2.y * wq[5] + q3.x * wq[6] + q3.y * wq[7];
    }
    d0 += __shfl_xor(d0, 1, 64); d0 += __shfl_xor(d0, 2, 64);
    d0 += __shfl_xor(d0, 4, 64); d0 += __shfl_xor(d0, 8, 64);
    d1 += __shfl_xor(d1, 1, 64); d1 += __shfl_xor(d1, 2, 64);
    d1 += __shfl_xor(d1, 4, 64); d1 += __shfl_xor(d1, 8, 64);
    if (kp == 0) {
      gstore(dst0 + col, d0 + bkS[col]);
      gstore(dst1 + col, d1 + bkS[col]);
    }
  };

  // ---- t=0 init per pipe ----
  auto initPipe = [&](Pipe& P) {
    if (tid < 256) {
      int e = cg * 256 + tid;          // 16384 floats over 64 blocks
      gstore(P.MB0 + e, 0.f);
      int r = e >> 11, s = (e >> 8) & 7, hd = e & 255;
      gstore(mem_out + ((size_t)(P.row0 + r) * NS + s) * HDIM + hd,
             Xp[(size_t)(P.row0 + r) * HDIM + hd]);
    }
    if (cg == 0 && tid < 64) gstore(probs_out + P.row0 * NS + tid, 0.f);
    {
      int r = tid >> 6, c4 = (tid & 63) * 4;   // prestage hloc = Xp[t=1] (pack f16)
      const float* src = &Xp[((size_t)BATCH + P.row0 + r) * HDIM + c4];
      float4 a = *(const float4*)src;
      *(uint2*)&P.hloc[r * 132 + c4 / 2] = make_uint2(pack2(a.x, a.y), pack2(a.z, a.w));
    }
  };
  // S1a for t=1: q from Xp[1], k from Xp[0] broadcast to all slots
  auto s1aInit = [&](Pipe& P) {
    int col = lane >> 4, kp = lane & 15;
    {
      const float* Wc = WQS + col * 260 + kp * 16;
      const float* Ak = Xp + ((size_t)BATCH + P.row0 + w) * HDIM + kp * 16;
      float d = 0.f;
#pragma unroll
      for (int k4 = 0; k4 < 4; ++k4) {
        float4 a = *(const float4*)(Ak + 4 * k4);
        d += a.x * Wc[4 * k4] + a.y * Wc[4 * k4 + 1] + a.z * Wc[4 * k4 + 2] + a.w * Wc[4 * k4 + 3];
      }
      d += __shfl_xor(d, 1, 64); d += __shfl_xor(d, 2, 64);
      d += __shfl_xor(d, 4, 64); d += __shfl_xor(d, 8, 64);
      if (kp == 0) gstore(P.QPRE + w * HDIM + QC0 + col, d + bqS[col]);
    }
    {
      const float* Wc = WKS + col * 260 + kp * 16;
      const float* Ak = Xp + (size_t)(P.row0 + w) * HDIM + kp * 16;
      float d = 0.f;
#pragma unroll
      for (int k4 = 0; k4 < 4; ++k4) {
        float4 a = *(const float4*)(Ak + 4 * k4);
        d += a.x * Wc[4 * k4] + a.y * Wc[4 * k4 + 1] + a.z * Wc[4 * k4 + 2] + a.w * Wc[4 * k4 + 3];
      }
      d += __shfl_xor(d, 1, 64); d += __shfl_xor(d, 2, 64);
      d += __shfl_xor(d, 4, 64); d += __shfl_xor(d, 8, 64);
      if (kp == 0) {
        float vk = d + bkS[col];
#pragma unroll
        for (int s = 0; s < NS; ++s) gstore(P.KPRE + (w * 8 + s) * HDIM + QC0 + col, vk);
      }
    }
  };

  // ---- merged H section: load both pipes' data in one burst, then compute ----
  auto hSecM = [&](int ci, int t, float* memCur, float4 hv0, float4 hv1) {
    const int hd0 = lane * 4;
    const uint* z0r = P0.Z2u + w * 512;
    const uint* z1r = P1.Z2u + w * 512;
    // ---- one merged gather burst (f16x2) ----
    uint2 cu0 = gloadu2(z0r + 384 + lane * 2);
    uint2 cu1 = gloadu2(z1r + 384 + lane * 2);
    uint2 ga0 = gloadu2(z0r + 6 * lane), gb0 = gloadu2(z0r + 6 * lane + 2), gc0 = gloadu2(z0r + 6 * lane + 4);
    uint2 ga1 = gloadu2(z1r + 6 * lane), gb1 = gloadu2(z1r + 6 * lane + 2), gc1 = gloadu2(z1r + 6 * lane + 4);
    float4 ls4 = *(const float4*)&LNS_[hd0];
    float4 lb4 = *(const float4*)&LNB_[hd0];
    float lsv[4] = {ls4.x, ls4.y, ls4.z, ls4.w};
    float lbv[4] = {lb4.x, lb4.y, lb4.z, lb4.w};
#pragma unroll
    for (int p = 0; p < 2; ++p) {
      Pipe& P = p ? P1 : P0;
      float cc[4];
      {
        uint2 cu = p ? cu1 : cu0;
        float2 x = unpack2(cu.x), y = unpack2(cu.y);
        cc[0] = x.x; cc[1] = x.y; cc[2] = y.x; cc[3] = y.y;
      }
      float g[12];
      {
        uint2 a = p ? ga1 : ga0, b = p ? gb1 : gb0, c = p ? gc1 : gc0;
        float2 t0 = unpack2(a.x), t1 = unpack2(a.y), t2 = unpack2(b.x),
               t3 = unpack2(b.y), t4 = unpack2(c.x), t5 = unpack2(c.y);
        g[0] = t0.x; g[1] = t0.y; g[2] = t1.x; g[3] = t1.y;
        g[4] = t2.x; g[5] = t2.y; g[6] = t3.x; g[7] = t3.y;
        g[8] = t4.x; g[9] = t4.y; g[10] = t5.x; g[11] = t5.y;
      }
      float4 hv = p ? hv1 : hv0;
      float s1 = cc[0] + cc[1] + cc[2] + cc[3];
      float s2 = cc[0] * cc[0] + cc[1] * cc[1] + cc[2] * cc[2] + cc[3] * cc[3];
#pragma unroll
      for (int m = 1; m < 64; m <<= 1) { s1 += __shfl_xor(s1, m, 64); s2 += __shfl_xor(s2, m, 64); }
      float mean = s1 * (1.f / 256.f);
      float inv = rsqrtf(s2 * (1.f / 256.f) - mean * mean + 1e-5f);
      float viv[4];
      {
        uint2 vu = *(const uint2*)&P.hloc[w * 132 + lane * 2];
        float2 x = unpack2(vu.x), y = unpack2(vu.y);
        viv[0] = x.x; viv[1] = x.y; viv[2] = y.x; viv[3] = y.y;
      }
      float4 xp4 = *(const float4*)&Xp[((size_t)t * BATCH + P.row0 + w) * HDIM + hd0];
      float xpv[4] = {xp4.x, xp4.y, xp4.z, xp4.w};
      float hivv[4] = {hv.x, hv.y, hv.z, hv.w};
      float cp = P.cpS[w * 8 + ci];
      float hn[4];
#pragma unroll
      for (int j = 0; j < 4; ++j) {
        float z0 = g[3 * j], z1v = g[3 * j + 1], z2g = g[3 * j + 2];
        float gm = fmaxf(z0, fmaxf(z1v, z2g));
        float e0 = __expf(z0 - gm), e1 = __expf(z1v - gm), e2 = __expf(z2g - gm);
        float act = ftanh((cc[j] - mean) * inv * lsv[j] + lbv[j]);
        float hc = (e0 * viv[j] + e1 * hivv[j] + e2 * act) * __builtin_amdgcn_rcpf(e0 + e1 + e2);
        hn[j] = xpv[j] * (1.f - cp) + hc * cp;
      }
      *(uint2*)&P.hloc[w * 132 + lane * 2] =
          make_uint2(pack2(hn[0], hn[1]), pack2(hn[2], hn[3]));
      if (lane == cg) {
        float* mp = memCur + ((size_t)(P.row0 + w) * NS + ci) * HDIM + QC0;
        gstore2(mp, hn[0], hn[1]);
        gstore2(mp + 2, hn[2], hn[3]);
      }
    }
  };

  // ---- cell section 1: merged Z2(ci), MFMA with direct-from-ws A fragments ----
  auto cellS1M = [&](int phRdy) {
    waitBoth(phRdy);
    const int row16 = lane & 15, kg = lane >> 4;
    const uint* zrow = (row16 < 8) ? (P0.Z1u + row16 * 512) : (P1.Z1u + (row16 - 8) * 512);
    const int kb = w * 16 + kg * 4;   // uint offset within 128-uint chunk window
    // batched coherent loads: 4 chunks x 2 ull (A fragments)
    ull a0 = gloadU(zrow + kb),       a1 = gloadU(zrow + kb + 2);
    ull b0 = gloadU(zrow + 128 + kb), b1 = gloadU(zrow + 128 + kb + 2);
    ull c0 = gloadU(zrow + 256 + kb), c1 = gloadU(zrow + 256 + kb + 2);
    ull d0 = gloadU(zrow + 384 + kb), d1 = gloadU(zrow + 384 + kb + 2);
    f32x4 acc = {0.f, 0.f, 0.f, 0.f};
    uint4 w0 = *(const uint4*)&W2b[row16 * 516 + 0 * 128 + kb];
    uint4 w1v = *(const uint4*)&W2b[row16 * 516 + 1 * 128 + kb];
    uint4 w2v = *(const uint4*)&W2b[row16 * 516 + 2 * 128 + kb];
    uint4 w3v = *(const uint4*)&W2b[row16 * 516 + 3 * 128 + kb];
    acc = __builtin_amdgcn_mfma_f32_16x16x32_f16(mk8(a0, a1), bc8(w0), acc, 0, 0, 0);
    acc = __builtin_amdgcn_mfma_f32_16x16x32_f16(mk8(b0, b1), bc8(w1v), acc, 0, 0, 0);
    acc = __builtin_amdgcn_mfma_f32_16x16x32_f16(mk8(c0, c1), bc8(w2v), acc, 0, 0, 0);
    acc = __builtin_amdgcn_mfma_f32_16x16x32_f16(mk8(d0, d1), bc8(w3v), acc, 0, 0, 0);
    redFinishMF(acc, P0.Z2u, P1.Z2u, b2s, false);
  };

  // ---- cell section 2: window + H(ci) + merged Z1(ci+1) via MFMA ----
  auto cellS2M = [&](int ci, int t, int phA, float* memCur) {
    const bool lastT = (t == T_LEN - 1);
    // hiv (Ast slot ci, row w) for both pipes before restage
    float4 hv0, hv1;
    {
      uint2 u0 = *(const uint2*)&Ast0[w * 132 + lane * 2];
      uint2 u1 = *(const uint2*)&Ast1[w * 132 + lane * 2];
      float2 a = unpack2(u0.x), b = unpack2(u0.y), c = unpack2(u1.x), d = unpack2(u1.y);
      hv0 = make_float4(a.x, a.y, b.x, b.y);
      hv1 = make_float4(c.x, c.y, d.x, d.y);
    }
    __syncthreads();
    if (ci < 7) {
      // restage both Ast = MbNew slot ci+1 (fully blended in P1), pack f16
      float* MbN0 = (t & 1) ? P0.MB1 : P0.MB0;
      float* MbN1 = (t & 1) ? P1.MB1 : P1.MB0;
      const int r16 = tid >> 5, c8 = (tid & 31) * 8, rr = r16 & 7;
      float* mb = (r16 < 8) ? MbN0 : MbN1;
      uint* as = (r16 < 8) ? Ast0 : Ast1;
      const float* src = mb + (rr * NS + ci + 1) * HDIM + c8;
      float2 a0 = gload2(src), a1 = gload2(src + 2), a2 = gload2(src + 4), a3 = gload2(src + 6);
      *(uint4*)&as[rr * 132 + c8 / 2] = make_uint4(
          pack2(a0.x, a0.y), pack2(a1.x, a1.y), pack2(a2.x, a2.y), pack2(a3.x, a3.y));
    } else if (!lastT) {
      // KPRE(s=6) from memCur slot 6 (visible: waited sigB(6) in cellS1(7))
      projK_G2(memCur + ((size_t)(P0.row0 + w) * NS + 6) * HDIM,
               memCur + ((size_t)(P1.row0 + w) * NS + 6) * HDIM,
               P0.KPRE + (w * 8 + 6) * HDIM + QC0,
               P1.KPRE + (w * 8 + 6) * HDIM + QC0);
    }
    __syncthreads();
    f32x4 bacc = {0.f, 0.f, 0.f, 0.f};
    if (ci < 7) z1Mfma(Ast0, Ast1, 128, bacc);   // Mn-half of Z1(ci+1)
    waitBoth(phA);
    hSecM(ci, t, memCur, hv0, hv1);
    __syncthreads();
    if (ci < 7) {
      z1Mfma(hloc0, hloc1, 0, bacc);   // h-half of Z1(ci+1)
      redFinishMF(bacc, P0.Z1u, P1.Z1u, b1s, true);
    } else if (!lastT) {
      // KPRE(s=7) from new h (LDS f16) — pre-sigB
      projK_L2(&hloc0[w * 132], &hloc1[w * 132],
               P0.KPRE + (w * 8 + 7) * HDIM + QC0,
               P1.KPRE + (w * 8 + 7) * HDIM + QC0);
    }
  };

  // ---- B-window: S1a(t+1) pieces merged, drained by NEXT signal ----
  auto bWinM = [&](int ci, int t, float* memCur) {
    if (ci == 0) {
      projQ2(Xp + ((size_t)(t + 1) * BATCH + P0.row0 + w) * HDIM,
             Xp + ((size_t)(t + 1) * BATCH + P1.row0 + w) * HDIM,
             P0.QPRE + w * HDIM + QC0, P1.QPRE + w * HDIM + QC0);
    } else if (ci <= 6) {
      const int s = ci - 1;   // memCur slot s visible (waited sigB(s) in cellS1(ci))
      projK_G2(memCur + ((size_t)(P0.row0 + w) * NS + s) * HDIM,
               memCur + ((size_t)(P1.row0 + w) * NS + s) * HDIM,
               P0.KPRE + (w * 8 + s) * HDIM + QC0,
               P1.KPRE + (w * 8 + s) * HDIM + QC0);
    } else {
      // prestage hloc = Xp[t+1] for both pipes (merged 16-row pass, pack f16)
      const int r16 = tid >> 5, c8 = (tid & 31) * 8, rr = r16 & 7;
      Pipe& P = (r16 < 8) ? P0 : P1;
      const float* src = &Xp[((size_t)(t + 1) * BATCH + P.row0 + rr) * HDIM + c8];
      float4 a = *(const float4*)src;
      float4 b = *(const float4*)(src + 4);
      *(uint4*)&P.hloc[rr * 132 + c8 / 2] = make_uint4(
          pack2(a.x, a.y), pack2(a.z, a.w), pack2(b.x, b.y), pack2(b.z, b.w));
    }
  };

  // ================= init + time loop =================
  __syncthreads();
  initPipe(P0); initPipe(P1);
  __syncthreads();
  s1aInit(P0); s1aInit(P1);
  int ph = 1;
  sigBoth(ph);
  waitBoth(ph);

  for (int t = 1; t < T_LEN; ++t) {
    const bool lastT = (t == T_LEN - 1);
    float* MbOld0 = ((t - 1) & 1) ? P0.MB1 : P0.MB0;
    float* MbOld1 = ((t - 1) & 1) ? P1.MB1 : P1.MB0;
    const float* memPrev = mem_out + (size_t)(t - 1) * BATCH * NS * HDIM;
    float* memCur = mem_out + (size_t)t * BATCH * NS * HDIM;
    const float* probsPrev = probs_out + (size_t)(t - 1) * BATCH * NS;
    float* probsCur = probs_out + (size_t)t * BATCH * NS;

    // ---------- P1 (merged pipes) ----------
    // (1) q-LN merged — pre-wait (QPRE(t) visible transitively); qln packed f16 -> Az0
    {
      const int r16 = tid >> 5, hd0 = (tid & 31) * 8, row = r16 & 7;
      Pipe& P = (r16 < 8) ? P0 : P1;
      float q[8]; float s1 = 0.f, s2 = 0.f;
#pragma unroll
      for (int j = 0; j < 4; ++j) {
        float2 v = gload2(P.QPRE + row * HDIM + hd0 + 2 * j);
        q[2 * j] = v.x; q[2 * j + 1] = v.y;
        s1 += v.x + v.y; s2 += v.x * v.x + v.y * v.y;
      }
#pragma unroll
      for (int m = 1; m < 32; m <<= 1) { s1 += __shfl_xor(s1, m, 64); s2 += __shfl_xor(s2, m, 64); }
      float mean = s1 * (1.f / 256.f);
      float inv = rsqrtf(s2 * (1.f / 256.f) - mean * mean + 1e-5f);
      float qn[8];
#pragma unroll
      for (int j = 0; j < 8; ++j)
        qn[j] = (q[j] - mean) * inv * lnqs[hd0 + j] + lnqb[hd0 + j];
      *(uint4*)&Az0[r16 * 132 + hd0 / 2] = make_uint4(
          pack2(qn[0], qn[1]), pack2(qn[2], qn[3]), pack2(qn[4], qn[5]), pack2(qn[6], qn[7]));
    }
    // wait for all blocks' B(7) of t-1 (KPRE fresh) — hidden under q-LN above
    waitBoth(ph);
    {
      // (2) k-LN + beta merged: 128 krows x 4 threads (one 64-float burst)
      const int kr128 = tid >> 2, u4 = tid & 3;
      Pipe& P = (kr128 < 64) ? P0 : P1;
      const int kr = kr128 & 63;
      const int rr16 = (kr >> 3) + ((kr128 < 64) ? 0 : 8);
      const float* kp = P.KPRE + kr * HDIM + u4 * 64;
      float kv[64]; float s1 = 0.f, s2 = 0.f;
#pragma unroll
      for (int e = 0; e < 32; ++e) {
        float2 v = gload2(kp + 2 * e);
        kv[2 * e] = v.x; kv[2 * e + 1] = v.y;
        s1 += v.x + v.y; s2 += v.x * v.x + v.y * v.y;
      }
      s1 += __shfl_xor(s1, 1, 64); s1 += __shfl_xor(s1, 2, 64);
      s2 += __shfl_xor(s2, 1, 64); s2 += __shfl_xor(s2, 2, 64);
      float mean = s1 * (1.f / 256.f);
      float inv = rsqrtf(s2 * (1.f / 256.f) - mean * mean + 1e-5f);
      float dot = 0.f;
#pragma unroll
      for (int e = 0; e < 64; e += 2) {
        int hd = u4 * 64 + e;
        float2 q2 = unpack2(Az0[rr16 * 132 + hd / 2]);
        float kl0 = (kv[e] - mean) * inv * LNKS_[hd] + LNKB_[hd];
        float kl1 = (kv[e + 1] - mean) * inv * LNKS_[hd + 1] + LNKB_[hd + 1];
        dot += fmaxf(q2.x + kl0, 0.f) * Wbs[hd];
        dot += fmaxf(q2.y + kl1, 0.f) * Wbs[hd + 1];
      }
      dot += __shfl_xor(dot, 1, 64); dot += __shfl_xor(dot, 2, 64);
      if (u4 == 0) P.betaS[kr] = (dot + bbetaS[0]) * 0.0625f;
    }
    __syncthreads();
    // (3) softmax + mask + p/cp/rcp (16 threads: 2 pipes x 8 rows)
    if (tid < 16) {
      Pipe& P = (tid < 8) ? P0 : P1;
      int r = tid & 7, b = P.row0 + r;
      float pp[8], pcp[8], run = 0.f;
#pragma unroll
      for (int s = 0; s < 8; s += 2) {
        float2 v = gload2(probsPrev + b * NS + s);
        pp[s] = v.x; pp[s + 1] = v.y;
      }
#pragma unroll
      for (int s = 0; s < 8; ++s) { run += pp[s]; pcp[s] = run; }
      float bmax = P.betaS[r * 8];
#pragma unroll
      for (int s = 1; s < 8; ++s) bmax = fmaxf(bmax, P.betaS[r * 8 + s]);
      float xm[8], ssum = 0.f;
#pragma unroll
      for (int s = 0; s < 8; ++s) {
        float mi = (s < 7) ? ((pcp[s + 1] < 1e-5f) ? 0.f : pcp[s + 1]) : 1.f;
        xm[s] = __expf(P.betaS[r * 8 + s] - bmax) * mi;
        ssum += fabsf(xm[s]);
      }
      float denom = fmaxf(ssum, 1e-12f);
      float run2 = 0.f, pn[8];
#pragma unroll
      for (int s = 0; s < 8; ++s) {
        pn[s] = xm[s] / denom; run2 += pn[s];
        P.cpS[r * 8 + s] = run2;
      }
      if (cg == tid) {   // 16 distinct writer blocks
#pragma unroll
        for (int s = 0; s < 8; s += 2) gstore2(probsCur + b * NS + s, pn[s], pn[s + 1]);
      }
      float run3 = 0.f;
#pragma unroll
      for (int s = 7; s >= 0; --s) { run3 += pn[s]; P.rcpS[r * 8 + s] = run3; }
    }
    __syncthreads();
    // (4) M-state owner update merged (2 pipes x 8r x 8s x 4c = 512 threads)
    {
      Pipe& P = (tid < 256) ? P0 : P1;
      float* MbOld = (tid < 256) ? MbOld0 : MbOld1;
      float* MbNew = (t & 1) ? P.MB1 : P.MB0;
      int e = tid & 255;
      int r = e >> 5, s = (e >> 2) & 7, c = e & 3;
      int idx = (r * NS + s) * HDIM + QC0 + c;
      float rc = P.rcpS[r * 8 + s];
      float mo = gload(MbOld + idx);
      float cm = gload(memPrev + ((size_t)(P.row0 + r) * NS + s) * HDIM + QC0 + c);
      gstore(MbNew + idx, mo * (1.f - rc) + cm * rc);
    }
    // (5) stage Ast = blend(MbOld, memPrev) slot0 merged, pack f16
    {
      const int r16 = tid >> 5, c8 = (tid & 31) * 8, rr = r16 & 7;
      Pipe& P = (r16 < 8) ? P0 : P1;
      float* MbOld = (r16 < 8) ? MbOld0 : MbOld1;
      float rc0 = P.rcpS[rr * 8];
      const float* mo = MbOld + (rr * NS) * HDIM + c8;
      const float* cm = memPrev + ((size_t)(P.row0 + rr) * NS) * HDIM + c8;
      float2 m0 = gload2(mo), m1 = gload2(mo + 2), m2 = gload2(mo + 4), m3 = gload2(mo + 6);
      float2 c0 = gload2(cm), c1 = gload2(cm + 2), c2 = gload2(cm + 4), c3 = gload2(cm + 6);
      uint* as = (r16 < 8) ? Ast0 : Ast1;
      *(uint4*)&as[rr * 132 + c8 / 2] = make_uint4(
          pack2(m0.x * (1.f - rc0) + c0.x * rc0, m0.y * (1.f - rc0) + c0.y * rc0),
          pack2(m1.x * (1.f - rc0) + c1.x * rc0, m1.y * (1.f - rc0) + c1.y * rc0),
          pack2(m2.x * (1.f - rc0) + c2.x * rc0, m2.y * (1.f - rc0) + c2.y * rc0),
          pack2(m3.x * (1.f - rc0) + c3.x * rc0, m3.y * (1.f - rc0) + c3.y * rc0));
    }
    __syncthreads();
    {
      // merged Z1(0) via MFMA: Mn-half (Ast) + h-half (hloc)
      f32x4 acc = {0.f, 0.f, 0.f, 0.f};
      z1Mfma(Ast0, Ast1, 128, acc);
      z1Mfma(hloc0, hloc1, 0, acc);
      redFinishMF(acc, P0.Z1u, P1.Z1u, b1s, true);
    }
    ++ph; sigBoth(ph);

    // ---------- cells ----------
    for (int ci = 0; ci < NS; ++ci) {
      const int phRdy = ph;
      cellS1M(phRdy);
      ++ph; sigBoth(ph);
      cellS2M(ci, t, ph, memCur);
      ++ph; sigBoth(ph);
      if (!lastT) bWinM(ci, t, memCur);
    }
    // no end-of-loop wait — next P1's q-LN runs pre-wait; waitBoth(ph) after q-LN
  }
}

extern "C" void kernel_launch(void* const* d_in, const int* in_sizes, int n_in,
                              void* d_out, int out_size, void* d_ws, size_t ws_size,
                              hipStream_t stream) {
  (void)in_sizes; (void)n_in; (void)out_size; (void)ws_size;
  const float* X     = (const float*)d_in[0];
  const float* Wp    = (const float*)d_in[3];
  const float* bp    = (const float*)d_in[4];
  const float* lns   = (const float*)d_in[5];
  const float* lnb   = (const float*)d_in[6];
  const float* Wq    = (const float*)d_in[7];
  const float* bq    = (const float*)d_in[8];
  const float* lnqs  = (const float*)d_in[9];
  const float* lnqb  = (const float*)d_in[10];
  const float* Wk    = (const float*)d_in[11];
  const float* bk    = (const float*)d_in[12];
  const float* lnks  = (const float*)d_in[13];
  const float* lnkb  = (const float*)d_in[14];
  const float* Wbeta = (const float*)d_in[15];
  const float* bbeta = (const float*)d_in[16];
  const float* W1    = (const float*)d_in[17];
  const float* b1    = (const float*)d_in[18];
  const float* W2    = (const float*)d_in[19];
  const float* b2    = (const float*)d_in[20];

  float* out       = (float*)d_out;
  float* out_xp    = out;
  float* out_mem   = out + (size_t)T_LEN * BATCH * HDIM;
  float* out_probs = out_mem + (size_t)T_LEN * BATCH * NS * HDIM;
  float* ws        = (float*)d_ws;

  hipLaunchKernelGGL(init_ctrl, dim3(4), dim3(256), 0, stream, (int*)d_ws);
  hipLaunchKernelGGL(xp_kernel, dim3(1024), dim3(256), 0, stream, X, Wp, bp, lns, lnb, out_xp);
  hipLaunchKernelGGL(omr_main, dim3(256), dim3(NTHR), 0, stream,
                     out_xp, Wq, bq, lnqs, lnqb, Wk, bk, lnks, lnkb, Wbeta, bbeta,
                     W1, b1, W2, b2, lns, lnb, out_mem, out_probs, ws);
}